// Round 1
// baseline (22970.709 us; speedup 1.0000x reference)
//
#include <hip/hip_runtime.h>
#include <hip/hip_cooperative_groups.h>
#include <math.h>

namespace cg = cooperative_groups;

#define BB 512
#define SS 64
#define TT 32
#define VV 128
#define EE 256
#define HH 512
#define DENC 1024
#define BH (BB*HH)
#define XW0 1792   // E + DENC + H
#define XW1 1024   // H + H
#define PW  1792   // H + DENC + E
#define G4H 2048   // 4*H

typedef __attribute__((ext_vector_type(8))) short bf16x8;
typedef __attribute__((ext_vector_type(4))) short bf16x4;
typedef __attribute__((ext_vector_type(4))) float f32x4;

__device__ __forceinline__ float sigf(float x){ return 1.f/(1.f+expf(-x)); }
__device__ __forceinline__ float bf2f(short s){
  return __uint_as_float(((unsigned)(unsigned short)s) << 16);
}
__device__ __forceinline__ short f2bf(float f){
  unsigned u = __float_as_uint(f);
  return (short)((u + 0x7FFF + ((u>>16)&1)) >> 16);   // RNE
}
__device__ __forceinline__ float tanh_fast(float x){
  x = fminf(fmaxf(x, -15.f), 15.f);
  float e = __expf(2.f*x);
  return (e - 1.f) / (e + 1.f);
}

// Double-buffered pipelined bf16 MFMA GEMM core. BK=64, one barrier per iter.
// LDS row stride 72 shorts (2-way bank aliasing only).
// Generalized: lda/ldb row strides, kBase starting column, nIter K-steps of 64.
// Wave w computes tile (BM/2)x(BN/2) at wm=(w>>1)*(BM/2), wn=(w&1)*(BN/2).
template<int BM, int BN>
struct GemmPipe {
  static constexpr int LA = 72;
  static __device__ __forceinline__ void run(short* Asb, short* Bsb,
      const short* __restrict__ A, const short* __restrict__ Bt,
      int lda, int ldb, int kBase, int nIter,
      int rowBase, int colBase, int tid, f32x4 acc[BM/32][BN/32])
  {
    constexpr int FI = BM/32, FJ = BN/32, ACH = BM/32, BCH = BN/32;
    const int lane = tid & 63, wave = tid >> 6;
    const int ml = lane & 15, kq = lane >> 4;
    const int wm = (wave >> 1)*(BM/2), wn = (wave & 1)*(BN/2);
    const int arow = (tid*ACH) >> 3, acol = ((tid*ACH) & 7)*8;
    const int brow = (tid*BCH) >> 3, bcol = ((tid*BCH) & 7)*8;
    const short* Ap = A + (size_t)(rowBase+arow)*lda + kBase + acol;
    const short* Bp = Bt + (size_t)(colBase+brow)*ldb + kBase + bcol;
    bf16x8 ar[ACH], br[BCH];
    #pragma unroll
    for (int c = 0; c < ACH; ++c) ar[c] = *(const bf16x8*)(Ap + c*8);
    #pragma unroll
    for (int c = 0; c < BCH; ++c) br[c] = *(const bf16x8*)(Bp + c*8);
    for (int i = 0; i < nIter; ++i) {
      short* Ab = Asb + (i&1)*(BM*LA);
      short* Bb = Bsb + (i&1)*(BN*LA);
      #pragma unroll
      for (int c = 0; c < ACH; ++c) *(bf16x8*)&Ab[arow*LA + acol + c*8] = ar[c];
      #pragma unroll
      for (int c = 0; c < BCH; ++c) *(bf16x8*)&Bb[brow*LA + bcol + c*8] = br[c];
      __syncthreads();
      if (i+1 < nIter) {
        const short* An = Ap + (size_t)(i+1)*64;
        const short* Bn = Bp + (size_t)(i+1)*64;
        #pragma unroll
        for (int c = 0; c < ACH; ++c) ar[c] = *(const bf16x8*)(An + c*8);
        #pragma unroll
        for (int c = 0; c < BCH; ++c) br[c] = *(const bf16x8*)(Bn + c*8);
      }
      #pragma unroll
      for (int kh = 0; kh < 2; ++kh) {
        bf16x8 af[FI], bfv[FJ];
        #pragma unroll
        for (int ii = 0; ii < FI; ++ii)
          af[ii] = *(const bf16x8*)&Ab[(wm + ii*16 + ml)*LA + kh*32 + kq*8];
        #pragma unroll
        for (int jj = 0; jj < FJ; ++jj)
          bfv[jj] = *(const bf16x8*)&Bb[(wn + jj*16 + ml)*LA + kh*32 + kq*8];
        #pragma unroll
        for (int ii = 0; ii < FI; ++ii)
          #pragma unroll
          for (int jj = 0; jj < FJ; ++jj)
            acc[ii][jj] = __builtin_amdgcn_mfma_f32_16x16x32_bf16(af[ii], bfv[jj], acc[ii][jj], 0,0,0);
      }
    }
    __syncthreads();
  }
};

// ---------------- persistent-kernel role functions ----------------

// attention for b = 2*bid, 2*bid+1 (no xcat0 emb write -- prewritten a step early)
__device__ __forceinline__ void attn_role(int bid, int tid, char* smem, int t,
    const short* __restrict__ enc_proj, const short* __restrict__ enc_out,
    const float* __restrict__ vvec, const int* __restrict__ mask,
    const int* __restrict__ targets, const short* __restrict__ embb,
    const short* __restrict__ hb, const short* __restrict__ wdecT,
    short* __restrict__ xcat0, short* __restrict__ predcat)
{
  const int b0 = bid*2;
  float* hbf = (float*)smem;                  // [2][512]
  float* dps = (float*)(smem + 4096);         // [ksel][b][512]
  float* vvf = (float*)(smem + 12288);        // [512]
  float* sc  = (float*)(smem + 14336);        // [2][64]
  float* wt  = (float*)(smem + 14848);        // [2][64]
  {
    bf16x4 h4 = *(const bf16x4*)&hb[(size_t)b0*HH + tid*4];
    #pragma unroll
    for (int j = 0; j < 4; ++j) hbf[tid*4 + j] = bf2f(h4[j]);
    vvf[tid] = vvec[tid];
    vvf[256 + tid] = vvec[256 + tid];
  }
  __syncthreads();
  // dec_proj partials: unit=(b,h8), 2 threads per unit (k-halves of 256)
  {
    int unit = tid & 127, ksel = tid >> 7;
    int bb = unit >> 6, h8 = unit & 63;
    const short* wp = wdecT + (size_t)(ksel*256)*HH + h8*8;
    const float* hrow = hbf + bb*HH + ksel*256;
    float a[8] = {0.f,0.f,0.f,0.f,0.f,0.f,0.f,0.f};
    for (int k = 0; k < 256; ++k) {
      bf16x8 w8 = *(const bf16x8*)(wp + (size_t)k*HH);
      float x = hrow[k];
      #pragma unroll
      for (int j = 0; j < 8; ++j) a[j] += x * bf2f(w8[j]);
    }
    float* d = dps + (ksel*2 + bb)*HH + h8*8;
    #pragma unroll
    for (int j = 0; j < 8; ++j) d[j] = a[j];
  }
  __syncthreads();
  {   // combine k-halves
    int bb = tid >> 7, h0_ = (tid & 127)*4;
    f32x4 s0 = *(f32x4*)&dps[bb*HH + h0_];
    f32x4 s1 = *(f32x4*)&dps[(2 + bb)*HH + h0_];
    *(f32x4*)&dps[bb*HH + h0_] = s0 + s1;
  }
  __syncthreads();
  // scores: unit=(b,s), 2 lanes per unit (h-halves of 256)
  {
    int u = tid >> 1, khalf = tid & 1;
    int bb = u >> 6, s = u & 63;
    const short* ep = enc_proj + ((size_t)(b0+bb)*SS + s)*HH + khalf*256;
    const float* dpp = dps + bb*HH + khalf*256;
    const float* vp  = vvf + khalf*256;
    float accv = 0.f;
    for (int hc = 0; hc < 32; ++hc) {
      bf16x8 e8 = *(const bf16x8*)(ep + hc*8);
      f32x4 d0 = *(const f32x4*)(dpp + hc*8);
      f32x4 d1 = *(const f32x4*)(dpp + hc*8 + 4);
      f32x4 v0 = *(const f32x4*)(vp + hc*8);
      f32x4 v1 = *(const f32x4*)(vp + hc*8 + 4);
      #pragma unroll
      for (int j = 0; j < 4; ++j) accv += v0[j]*tanh_fast(d0[j] + bf2f(e8[j]));
      #pragma unroll
      for (int j = 0; j < 4; ++j) accv += v1[j]*tanh_fast(d1[j] + bf2f(e8[4+j]));
    }
    accv += __shfl_xor(accv, 1, 64);
    if (khalf == 0) sc[bb*64 + s] = accv;
  }
  __syncthreads();
  if (tid < 128) {   // masked softmax: wave0 -> b0, wave1 -> b1
    int bb = tid >> 6, s = tid & 63;
    int valid = mask[(b0+bb)*SS + s];
    float x = valid ? sc[bb*64 + s] : -INFINITY;
    float mx = x;
    #pragma unroll
    for (int off = 32; off; off >>= 1) mx = fmaxf(mx, __shfl_xor(mx, off, 64));
    float e = valid ? __expf(x - mx) : 0.f;
    float sum = e;
    #pragma unroll
    for (int off = 32; off; off >>= 1) sum += __shfl_xor(sum, off, 64);
    wt[bb*64 + s] = e / sum;
  }
  __syncthreads();
  {   // context
    int bb = tid >> 7, d0 = (tid & 127)*8;
    const short* eob = enc_out + (size_t)(b0+bb)*SS*DENC + d0;
    float ca[8] = {0.f,0.f,0.f,0.f,0.f,0.f,0.f,0.f};
    for (int s = 0; s < SS; ++s) {
      float w = wt[bb*64 + s];
      bf16x8 e8 = *(const bf16x8*)(eob + (size_t)s*DENC);
      #pragma unroll
      for (int j = 0; j < 8; ++j) ca[j] += w * bf2f(e8[j]);
    }
    bf16x8 cb8;
    #pragma unroll
    for (int j = 0; j < 8; ++j) cb8[j] = f2bf(ca[j]);
    int b_ = b0 + bb;
    *(bf16x8*)&xcat0[(size_t)b_*XW0 + EE + d0] = cb8;
    *(bf16x8*)&predcat[(size_t)b_*PW + HH + d0] = cb8;
  }
  #pragma unroll
  for (int bb = 0; bb < 2; ++bb) {   // predcat emb only (xcat0 emb prewritten)
    int b_ = b0 + bb;
    int tok = (t == 0) ? 2 : targets[b_*TT + t - 1];
    short ev = embb[tok*EE + tid];
    predcat[(size_t)b_*PW + HH + DENC + tid] = ev;
  }
}

__device__ __forceinline__ void out_role(int idx, int tid, char* smem,
    const short* __restrict__ predprev, const short* __restrict__ wout,
    const float* __restrict__ b_out, float* __restrict__ out, int t)
{
  short* As = (short*)smem;
  short* Bs = (short*)(smem + 18432);
  const int rowBase = (idx >> 1)*64, colBase = (idx & 1)*64;
  f32x4 acc[2][2];
  #pragma unroll
  for (int i = 0; i < 2; ++i)
    #pragma unroll
    for (int j = 0; j < 2; ++j) acc[i][j] = {0.f,0.f,0.f,0.f};
  GemmPipe<64,64>::run(As, Bs, predprev, wout, PW, PW, 0, PW/64, rowBase, colBase, tid, acc);
  const int lane = tid & 63, wave = tid >> 6, ml = lane & 15, kq = lane >> 4;
  const int wm = (wave >> 1)*32, wn = (wave & 1)*32;
  #pragma unroll
  for (int ii = 0; ii < 2; ++ii)
    #pragma unroll
    for (int jj = 0; jj < 2; ++jj) {
      int n = colBase + wn + jj*16 + ml;
      float bv = b_out[n];
      #pragma unroll
      for (int r2 = 0; r2 < 4; ++r2) {
        int m = rowBase + wm + ii*16 + kq*4 + r2;
        out[(size_t)m*(TT*VV) + (size_t)(t-1)*VV + n] = acc[ii][jj][r2] + bv;
      }
    }
}

__device__ __forceinline__ void pstore(int tid, int rowBase, int colBase,
    float* __restrict__ P, f32x4 acc[2][2])
{
  const int lane = tid & 63, wave = tid >> 6, ml = lane & 15, kq = lane >> 4;
  const int wm = (wave >> 1)*32, wn = (wave & 1)*32;
  #pragma unroll
  for (int ii = 0; ii < 2; ++ii)
    #pragma unroll
    for (int jj = 0; jj < 2; ++jj)
      #pragma unroll
      for (int r2 = 0; r2 < 4; ++r2)
        P[(size_t)(rowBase + wm + ii*16 + kq*4 + r2)*G4H + colBase + wn + jj*16 + ml] = acc[ii][jj][r2];
}

// gates GEMM finish (acc seeded from partial P) + fused LSTM cell epilogue.
__device__ __forceinline__ void gates_phase(int bid, int tid, char* smem,
    const short* __restrict__ A, const short* __restrict__ W,
    const float* __restrict__ bias, const float* __restrict__ P,
    float* __restrict__ cb, int lda, int kBase, int nIter,
    short* __restrict__ d1, int ld1, short* __restrict__ d2, int ld2,
    short* __restrict__ d3)
{
  short* As = (short*)smem;
  short* Bs = (short*)(smem + 18432);
  const int rowBase = (bid >> 5)*64, colBase = (bid & 31)*64;
  const int lane = tid & 63, wave = tid >> 6, ml = lane & 15, kq = lane >> 4;
  const int wm = (wave >> 1)*32, wn = (wave & 1)*32;
  f32x4 acc[2][2];
  const float* Pp = P + (size_t)rowBase*G4H + colBase;
  #pragma unroll
  for (int ii = 0; ii < 2; ++ii)
    #pragma unroll
    for (int jj = 0; jj < 2; ++jj)
      #pragma unroll
      for (int r2 = 0; r2 < 4; ++r2)
        acc[ii][jj][r2] = Pp[(wm + ii*16 + kq*4 + r2)*G4H + wn + jj*16 + ml];
  GemmPipe<64,64>::run(As, Bs, A, W, lda, lda, kBase, nIter, rowBase, colBase, tid, acc);
  float* Ct = (float*)smem;                    // 64*68*4 = 17408 <= 18432
  float bj0 = bias[colBase + wn + ml];
  float bj1 = bias[colBase + wn + 16 + ml];
  #pragma unroll
  for (int ii = 0; ii < 2; ++ii)
    #pragma unroll
    for (int jj = 0; jj < 2; ++jj)
      #pragma unroll
      for (int r2 = 0; r2 < 4; ++r2)
        Ct[(wm + ii*16 + kq*4 + r2)*68 + wn + jj*16 + ml] = acc[ii][jj][r2] + (jj ? bj1 : bj0);
  __syncthreads();
  #pragma unroll
  for (int kk = 0; kk < 4; ++kk) {
    int cidx = tid + kk*256;
    int m = cidx >> 4, hl = cidx & 15;
    float4 gv = *(float4*)&Ct[m*68 + hl*4];    // i,f,g,o
    int b_ = rowBase + m, h_ = (colBase >> 2) + hl;
    float cp = cb[b_*HH + h_];
    float cn = sigf(gv.y)*cp + sigf(gv.x)*tanhf(gv.z);
    float hn = sigf(gv.w)*tanhf(cn);
    cb[b_*HH + h_] = cn;
    short hb16 = f2bf(hn);
    d1[(size_t)b_*ld1 + h_] = hb16;
    d2[(size_t)b_*ld2 + h_] = hb16;
    if (d3) d3[(size_t)b_*HH + h_] = hb16;
  }
}

// write emb(token(t+1)) into next xcat0 buffer: 64 b-rows starting at rowBase
__device__ __forceinline__ void emb_prewrite(int rowBase, int tid,
    short* __restrict__ xc0n, const int* __restrict__ targets,
    const short* __restrict__ embb, int t)
{
  int b_ = rowBase + (tid >> 2);
  int tok = targets[b_*TT + t];
  const short* src = embb + tok*EE + (tid & 3)*64;
  short* dst = xc0n + (size_t)b_*XW0 + (tid & 3)*64;
  #pragma unroll
  for (int j = 0; j < 8; ++j)
    *(bf16x8*)(dst + j*8) = *(const bf16x8*)(src + j*8);
}

// ---------------- persistent cooperative decode kernel ----------------
// grid = 768 blocks x 256 thr (3 blocks/CU guaranteed by launch_bounds + 36KB LDS).
// Per step: phase1 = attn(256) || partial-gates0 K={emb,h0} (256) ||
//           partial-gates1 K=h1 (256, first 16 also do out-GEMM for t-1);
//           phase2 = gates0 finish (context K, 16 iters, acc from P0) + LSTM0;
//           phase3 = gates1 finish (h0n K, 8 iters, acc from P1) + LSTM1 + emb prewrite.
__global__ __launch_bounds__(256, 3)
void decode_persist(
    const short* __restrict__ enc_proj, const short* __restrict__ enc_out,
    const float* __restrict__ vvec, const int* __restrict__ mask,
    const int* __restrict__ targets, const short* __restrict__ embb,
    short* __restrict__ hb, const short* __restrict__ wdecT,
    short* __restrict__ xc0a, short* __restrict__ xc0b,
    short* __restrict__ xc1a, short* __restrict__ xc1b,
    short* __restrict__ pca, short* __restrict__ pcb,
    const short* __restrict__ wcat0, const short* __restrict__ wcat1,
    const float* __restrict__ bias0, const float* __restrict__ bias1,
    float* __restrict__ cbuf, float* __restrict__ P0, float* __restrict__ P1,
    const short* __restrict__ wout, const float* __restrict__ b_out,
    float* __restrict__ out)
{
  cg::grid_group grid = cg::this_grid();
  __shared__ __align__(16) char smem[36864];
  const int bid = blockIdx.x, tid = threadIdx.x;
  #pragma unroll 1
  for (int t = 0; t <= TT; ++t) {
    short* xc0c = (t & 1) ? xc0b : xc0a;
    short* xc0n = (t & 1) ? xc0a : xc0b;
    short* xc1c = (t & 1) ? xc1b : xc1a;
    short* xc1n = (t & 1) ? xc1a : xc1b;
    short* pcc  = (t & 1) ? pcb  : pca;
    short* pcn  = (t & 1) ? pca  : pcb;
    // ---------- phase 1 ----------
    if (bid < 256) {
      if (t < TT)
        attn_role(bid, tid, smem, t, enc_proj, enc_out, vvec, mask, targets,
                  embb, hb, wdecT, xc0c, pcc);
    } else if (bid < 512) {
      if (t < TT) {   // partial gates0: K in [0,256) U [1280,1792)
        short* As = (short*)smem; short* Bs = (short*)(smem + 18432);
        int idx = bid - 256;
        int rowBase = (idx >> 5)*64, colBase = (idx & 31)*64;
        f32x4 acc[2][2];
        #pragma unroll
        for (int i = 0; i < 2; ++i)
          #pragma unroll
          for (int j = 0; j < 2; ++j) acc[i][j] = {0.f,0.f,0.f,0.f};
        GemmPipe<64,64>::run(As, Bs, xc0c, wcat0, XW0, XW0, 0,    4, rowBase, colBase, tid, acc);
        GemmPipe<64,64>::run(As, Bs, xc0c, wcat0, XW0, XW0, 1280, 8, rowBase, colBase, tid, acc);
        pstore(tid, rowBase, colBase, P0, acc);
      }
    } else {
      if (t < TT) {   // partial gates1: K in [512,1024)
        short* As = (short*)smem; short* Bs = (short*)(smem + 18432);
        int idx = bid - 512;
        int rowBase = (idx >> 5)*64, colBase = (idx & 31)*64;
        f32x4 acc[2][2];
        #pragma unroll
        for (int i = 0; i < 2; ++i)
          #pragma unroll
          for (int j = 0; j < 2; ++j) acc[i][j] = {0.f,0.f,0.f,0.f};
        GemmPipe<64,64>::run(As, Bs, xc1c, wcat1, XW1, XW1, 512, 8, rowBase, colBase, tid, acc);
        pstore(tid, rowBase, colBase, P1, acc);
      }
      if (bid < 528 && t >= 1)
        out_role(bid - 512, tid, smem, pcn, wout, b_out, out, t);
    }
    if (t == TT) break;
    __threadfence(); grid.sync(); __threadfence();
    // ---------- phase 2: gates0 finish (context K) + LSTM0 ----------
    if (bid < 256)
      gates_phase(bid, tid, smem, xc0c, wcat0, bias0, P0, cbuf, XW0, 256, 16,
                  xc1c, XW1, xc0n + EE + DENC, XW0, (short*)nullptr);
    __threadfence(); grid.sync(); __threadfence();
    // ---------- phase 3: gates1 finish (h0n K) + LSTM1 + emb prewrite ----------
    if (bid < 256) {
      gates_phase(bid, tid, smem, xc1c, wcat1, bias1, P1, cbuf + BH, XW1, 0, 8,
                  xc1n + HH, XW1, pcc, PW, hb);
      if ((bid & 31) == 0 && t + 1 < TT)
        emb_prewrite((bid >> 5)*64, tid, xc0n, targets, embb, t);
    }
    __threadfence(); grid.sync(); __threadfence();
  }
}

// ---------------- fallback (original 3-kernel pipeline) ----------------

__global__ __launch_bounds__(256)
void gates_fused(const short* __restrict__ A, const short* __restrict__ W,
                 const float* __restrict__ bias, float* __restrict__ cb,
                 short* __restrict__ d1, short* __restrict__ d2, short* __restrict__ d3,
                 int K, int layer)
{
  __shared__ __align__(16) char smem[36864];
  short* As = (short*)smem;
  short* Bs = (short*)(smem + 18432);
  const int tid = threadIdx.x;
  const int rowBase = blockIdx.y*64, colBase = blockIdx.x*64;
  f32x4 acc[2][2];
  #pragma unroll
  for (int i = 0; i < 2; ++i)
    #pragma unroll
    for (int j = 0; j < 2; ++j) acc[i][j] = {0.f,0.f,0.f,0.f};
  GemmPipe<64,64>::run(As, Bs, A, W, K, K, 0, K >> 6, rowBase, colBase, tid, acc);
  const int lane = tid & 63, wave = tid >> 6, ml = lane & 15, kq = lane >> 4;
  const int wm = (wave >> 1)*32, wn = (wave & 1)*32;
  float* Ct = (float*)smem;
  float bj0 = bias[colBase + wn + ml];
  float bj1 = bias[colBase + wn + 16 + ml];
  #pragma unroll
  for (int ii = 0; ii < 2; ++ii)
    #pragma unroll
    for (int jj = 0; jj < 2; ++jj)
      #pragma unroll
      for (int r2 = 0; r2 < 4; ++r2)
        Ct[(wm + ii*16 + kq*4 + r2)*68 + wn + jj*16 + ml] = acc[ii][jj][r2] + (jj ? bj1 : bj0);
  __syncthreads();
  #pragma unroll
  for (int kk = 0; kk < 4; ++kk) {
    int cidx = tid + kk*256;
    int m = cidx >> 4, hl = cidx & 15;
    float4 gv = *(float4*)&Ct[m*68 + hl*4];
    int b_ = rowBase + m, h_ = (colBase >> 2) + hl;
    float cp = cb[b_*HH + h_];
    float cn = sigf(gv.y)*cp + sigf(gv.x)*tanhf(gv.z);
    float hn = sigf(gv.w)*tanhf(cn);
    cb[b_*HH + h_] = cn;
    short hb16 = f2bf(hn);
    if (layer == 0) {
      d1[(size_t)b_*XW1 + h_] = hb16;
      d2[(size_t)b_*XW0 + h_] = hb16;
    } else {
      d1[(size_t)b_*XW1 + h_] = hb16;
      d2[(size_t)b_*PW  + h_] = hb16;
      d3[(size_t)b_*HH  + h_] = hb16;
    }
  }
}

__global__ __launch_bounds__(256)
void attn_out(const short* __restrict__ enc_proj, const short* __restrict__ enc_out,
              const float* __restrict__ vvec, const int* __restrict__ mask,
              const int* __restrict__ targets, const short* __restrict__ embb,
              const short* __restrict__ hb, const short* __restrict__ wdecT,
              short* __restrict__ xcat0, short* __restrict__ predcat,
              const short* __restrict__ predprev, const short* __restrict__ wout,
              const float* __restrict__ b_out, float* __restrict__ out, int t)
{
  __shared__ __align__(16) char smem[36864];
  const int tid = threadIdx.x;
  if (blockIdx.x >= 256) {
    if (t == 0) return;
    int idx = blockIdx.x - 256;
    out_role(idx, tid, smem, predprev, wout, b_out, out, t);
    return;
  }
  if (t >= TT) return;
  attn_role(blockIdx.x, tid, smem, t, enc_proj, enc_out, vvec, mask, targets,
            embb, hb, wdecT, xcat0, predcat);
  // fallback path: also write xcat0 emb (no prewrite pipeline here)
  #pragma unroll
  for (int bb = 0; bb < 2; ++bb) {
    int b_ = blockIdx.x*2 + bb;
    int tok = (t == 0) ? 2 : targets[b_*TT + t - 1];
    xcat0[(size_t)b_*XW0 + tid] = embb[tok*EE + tid];
  }
}

// enc_proj = enc_out @ W_enc.T (M=32768, N=512, K=1024), bf16 out. BM=64, BN=128.
__global__ __launch_bounds__(256)
void enc_gemm(short* __restrict__ C, const short* __restrict__ A, const short* __restrict__ Bt,
              int K, int ldc)
{
  __shared__ __align__(16) char smem[55296];
  short* As = (short*)smem;                    // 2*64*72*2  = 18432
  short* Bs = (short*)(smem + 18432);          // 2*128*72*2 = 36864
  const int tid = threadIdx.x;
  const int rowBase = blockIdx.y*64, colBase = blockIdx.x*128;
  f32x4 acc[2][4];
  #pragma unroll
  for (int i = 0; i < 2; ++i)
    #pragma unroll
    for (int j = 0; j < 4; ++j) acc[i][j] = {0.f,0.f,0.f,0.f};
  GemmPipe<64,128>::run(As, Bs, A, Bt, K, K, 0, K >> 6, rowBase, colBase, tid, acc);
  const int lane = tid & 63, wave = tid >> 6, ml = lane & 15, kq = lane >> 4;
  const int wm = (wave >> 1)*32, wn = (wave & 1)*64;
  #pragma unroll
  for (int ii = 0; ii < 2; ++ii)
    #pragma unroll
    for (int jj = 0; jj < 4; ++jj) {
      int n = colBase + wn + jj*16 + ml;
      #pragma unroll
      for (int r2 = 0; r2 < 4; ++r2) {
        int m = rowBase + wm + ii*16 + kq*4 + r2;
        C[(size_t)m*ldc + n] = f2bf(acc[ii][jj][r2]);
      }
    }
}

// interleaved (n = 4*h + gate) bf16 weight concat
__global__ __launch_bounds__(256)
void build_wcat_bf(short* __restrict__ wcat0, short* __restrict__ wcat1,
                   const float* __restrict__ wih0, const float* __restrict__ whh0,
                   const float* __restrict__ wih1, const float* __restrict__ whh1)
{
  int idx = blockIdx.x*256 + threadIdx.x;
  const int N0 = G4H*XW0;
  if (idx < N0) {
    int n = idx / XW0, k = idx % XW0;
    int row = (n & 3)*HH + (n >> 2);
    float v = (k < EE+DENC) ? wih0[(size_t)row*(EE+DENC) + k] : whh0[(size_t)row*HH + (k - (EE+DENC))];
    wcat0[idx] = f2bf(v);
  } else {
    int j = idx - N0;
    int n = j / XW1, k = j % XW1;
    int row = (n & 3)*HH + (n >> 2);
    float v = (k < HH) ? wih1[(size_t)row*HH + k] : whh1[(size_t)row*HH + (k - HH)];
    wcat1[j] = f2bf(v);
  }
}

__global__ __launch_bounds__(256)
void cvt_encout(short* __restrict__ dst, const float* __restrict__ src)
{
  size_t i8 = ((size_t)blockIdx.x*256 + threadIdx.x)*8;
  float4 a = *(const float4*)&src[i8];
  float4 b = *(const float4*)&src[i8+4];
  bf16x8 o;
  o[0]=f2bf(a.x); o[1]=f2bf(a.y); o[2]=f2bf(a.z); o[3]=f2bf(a.w);
  o[4]=f2bf(b.x); o[5]=f2bf(b.y); o[6]=f2bf(b.z); o[7]=f2bf(b.w);
  *(bf16x8*)&dst[i8] = o;
}

__global__ __launch_bounds__(256)
void prep_misc(float* __restrict__ cbuf, short* __restrict__ xcat0a, short* __restrict__ xcat1a,
               short* __restrict__ hb, short* __restrict__ wdecT, short* __restrict__ wenc,
               short* __restrict__ wout, short* __restrict__ embb,
               float* __restrict__ bias0i, float* __restrict__ bias1i,
               const float* __restrict__ c0, const float* __restrict__ h0,
               const float* __restrict__ W_dec, const float* __restrict__ W_enc,
               const float* __restrict__ W_out, const float* __restrict__ emb,
               const float* __restrict__ b_ih0, const float* __restrict__ b_hh0,
               const float* __restrict__ b_ih1, const float* __restrict__ b_hh1)
{
  int idx = blockIdx.x*256 + threadIdx.x;
  if (idx < 524288) { cbuf[idx] = c0[idx]; return; }
  idx -= 524288;
  if (idx < 262144) {
    int b = idx >> 9, h = idx & 511;
    xcat0a[(size_t)b*XW0 + EE + DENC + h] = f2bf(h0[idx]);
    return;
  }
  idx -= 262144;
  if (idx < 262144) {
    int b = idx >> 9, h = idx & 511;
    short v = f2bf(h0[BH + idx]);
    xcat1a[(size_t)b*XW1 + HH + h] = v;
    hb[idx] = v;
    return;
  }
  idx -= 262144;
  if (idx < 262144) {                           // wdecT[k][n] = W_dec[n][k]
    int k = idx >> 9, n = idx & 511;
    wdecT[idx] = f2bf(W_dec[(size_t)n*HH + k]);
    return;
  }
  idx -= 262144;
  if (idx < 524288) { wenc[idx] = f2bf(W_enc[idx]); return; }
  idx -= 524288;
  if (idx < 229376) { wout[idx] = f2bf(W_out[idx]); return; }
  idx -= 229376;
  if (idx < 32768)  { embb[idx] = f2bf(emb[idx]); return; }
  idx -= 32768;
  if (idx < 2048) {
    int row = (idx & 3)*HH + (idx >> 2);
    bias0i[idx] = b_ih0[row] + b_hh0[row];
    return;
  }
  idx -= 2048;
  if (idx < 2048) {
    int row = (idx & 3)*HH + (idx >> 2);
    bias1i[idx] = b_ih1[row] + b_hh1[row];
    return;
  }
  idx -= 2048;
  {                                             // emb(t=0) = emb[EOS=2] into xcat0a
    int b = idx >> 8, e = idx & 255;
    xcat0a[(size_t)b*XW0 + e] = f2bf(emb[2*EE + e]);
  }
}

extern "C" void kernel_launch(void* const* d_in, const int* in_sizes, int n_in,
                              void* d_out, int out_size, void* d_ws, size_t ws_size,
                              hipStream_t stream) {
  const float* enc_out = (const float*)d_in[0];
  const float* h0      = (const float*)d_in[1];
  const float* c0      = (const float*)d_in[2];
  const int*   targets = (const int*)d_in[3];
  const int*   mask    = (const int*)d_in[4];
  const float* emb     = (const float*)d_in[5];
  const float* W_enc   = (const float*)d_in[6];
  const float* W_dec   = (const float*)d_in[7];
  const float* v       = (const float*)d_in[8];
  const float* b_ih0   = (const float*)d_in[11];
  const float* b_hh0   = (const float*)d_in[12];
  const float* b_ih1   = (const float*)d_in[15];
  const float* b_hh1   = (const float*)d_in[16];
  const float* b_out   = (const float*)d_in[18];
  float* out = (float*)d_out;

  char* ws = (char*)d_ws;
  size_t o = 0;
  short* enc_out_bf = (short*)(ws + o); o += (size_t)BB*SS*DENC*2;
  short* enc_proj_bf= (short*)(ws + o); o += (size_t)BB*SS*HH*2;
  short* wcat0i     = (short*)(ws + o); o += (size_t)G4H*XW0*2;
  short* wcat1i     = (short*)(ws + o); o += (size_t)G4H*XW1*2;
  short* wdecT      = (short*)(ws + o); o += (size_t)HH*HH*2;
  short* wenc_bf    = (short*)(ws + o); o += (size_t)HH*DENC*2;
  short* wout_bf    = (short*)(ws + o); o += (size_t)VV*PW*2;
  short* emb_bf     = (short*)(ws + o); o += (size_t)VV*EE*2;
  short* xcat0a     = (short*)(ws + o); o += (size_t)BB*XW0*2;
  short* xcat0b     = (short*)(ws + o); o += (size_t)BB*XW0*2;
  short* xcat1a     = (short*)(ws + o); o += (size_t)BB*XW1*2;
  short* xcat1b     = (short*)(ws + o); o += (size_t)BB*XW1*2;
  short* predcata   = (short*)(ws + o); o += (size_t)BB*PW*2;
  short* predcatb   = (short*)(ws + o); o += (size_t)BB*PW*2;
  short* hb         = (short*)(ws + o); o += (size_t)BH*2;
  float* cbuf       = (float*)(ws + o); o += (size_t)2*BH*4;
  float* bias0i     = (float*)(ws + o); o += (size_t)G4H*4;
  float* bias1i     = (float*)(ws + o); o += (size_t)G4H*4;
  float* P0         = (float*)(ws + o); o += (size_t)BB*G4H*4;
  float* P1         = (float*)(ws + o); o += (size_t)BB*G4H*4;
  (void)ws_size; (void)in_sizes; (void)n_in; (void)out_size;

  cvt_encout<<<16384, 256, 0, stream>>>(enc_out_bf, enc_out);
  build_wcat_bf<<<22528, 256, 0, stream>>>(wcat0i, wcat1i,
      (const float*)d_in[9], (const float*)d_in[10], (const float*)d_in[13], (const float*)d_in[14]);
  prep_misc<<<8720, 256, 0, stream>>>(cbuf, xcat0a, xcat1a, hb, wdecT, wenc_bf, wout_bf, emb_bf,
      bias0i, bias1i, c0, h0, W_dec, W_enc, (const float*)d_in[17], emb,
      b_ih0, b_hh0, b_ih1, b_hh1);
  enc_gemm<<<dim3(HH/128, (BB*SS)/64), 256, 0, stream>>>(
      enc_proj_bf, enc_out_bf, wenc_bf, DENC, HH);

  void* kargs[] = {
    (void*)&enc_proj_bf, (void*)&enc_out_bf, (void*)&v, (void*)&mask,
    (void*)&targets, (void*)&emb_bf, (void*)&hb, (void*)&wdecT,
    (void*)&xcat0a, (void*)&xcat0b, (void*)&xcat1a, (void*)&xcat1b,
    (void*)&predcata, (void*)&predcatb, (void*)&wcat0i, (void*)&wcat1i,
    (void*)&bias0i, (void*)&bias1i, (void*)&cbuf, (void*)&P0, (void*)&P1,
    (void*)&wout_bf, (void*)&b_out, (void*)&out
  };
  hipError_t cerr = hipLaunchCooperativeKernel((void*)decode_persist,
      dim3(768), dim3(256), kargs, 0, stream);
  if (cerr != hipSuccess) {
    (void)hipGetLastError();   // clear sticky error; fall back to 3-kernel loop
    short* xc0[2] = {xcat0a, xcat0b};
    short* xc1[2] = {xcat1a, xcat1b};
    short* pc[2]  = {predcata, predcatb};
    for (int t = 0; t < TT; ++t) {
      attn_out<<<272, 256, 0, stream>>>(enc_proj_bf, enc_out_bf, v, mask, targets, emb_bf,
          hb, wdecT, xc0[t&1], pc[t&1], pc[(t+1)&1], wout_bf, b_out, out, t);
      gates_fused<<<dim3(G4H/64, BB/64), 256, 0, stream>>>(
          xc0[t&1], wcat0i, bias0i, cbuf, xc1[t&1], xc0[(t+1)&1] + EE + DENC, (short*)nullptr, XW0, 0);
      gates_fused<<<dim3(G4H/64, BB/64), 256, 0, stream>>>(
          xc1[t&1], wcat1i, bias1i, cbuf + BH, xc1[(t+1)&1] + HH, pc[t&1], hb, XW1, 1);
    }
    attn_out<<<272, 256, 0, stream>>>(enc_proj_bf, enc_out_bf, v, mask, targets, emb_bf,
        hb, wdecT, xc0[0], pc[0], pc[1], wout_bf, b_out, out, TT);
  }
}

// Round 2
// 6810.677 us; speedup vs baseline: 3.3727x; 3.3727x over previous
//
#include <hip/hip_runtime.h>
#include <math.h>

#define BB 512
#define SS 64
#define TT 32
#define VV 128
#define EE 256
#define HH 512
#define DENC 1024
#define BH (BB*HH)
#define XW0 1792   // E + DENC + H
#define XW1 1024   // H + H
#define PW  1792   // H + DENC + E
#define G4H 2048   // 4*H
#define NBLK 768u

typedef __attribute__((ext_vector_type(8))) short bf16x8;
typedef __attribute__((ext_vector_type(4))) short bf16x4;
typedef __attribute__((ext_vector_type(4))) float f32x4;

__device__ __forceinline__ float sigf(float x){ return 1.f/(1.f+expf(-x)); }
__device__ __forceinline__ float bf2f(short s){
  return __uint_as_float(((unsigned)(unsigned short)s) << 16);
}
__device__ __forceinline__ short f2bf(float f){
  unsigned u = __float_as_uint(f);
  return (short)((u + 0x7FFF + ((u>>16)&1)) >> 16);   // RNE
}
__device__ __forceinline__ float tanh_fast(float x){
  x = fminf(fmaxf(x, -15.f), 15.f);
  float e = __expf(2.f*x);
  return (e - 1.f) / (e + 1.f);
}

// ---- agent-scope coherent (L2-bypassing, no-fence) payload access ----
__device__ __forceinline__ unsigned long long coh_ld64(const void* p){
  return __hip_atomic_load((unsigned long long*)p, __ATOMIC_RELAXED, __HIP_MEMORY_SCOPE_AGENT);
}
__device__ __forceinline__ void coh_st64(void* p, unsigned long long v){
  __hip_atomic_store((unsigned long long*)p, v, __ATOMIC_RELAXED, __HIP_MEMORY_SCOPE_AGENT);
}
__device__ __forceinline__ float coh_ldf(const float* p){
  return __hip_atomic_load((float*)p, __ATOMIC_RELAXED, __HIP_MEMORY_SCOPE_AGENT);
}
__device__ __forceinline__ void coh_stf(float* p, float v){
  __hip_atomic_store((float*)p, v, __ATOMIC_RELAXED, __HIP_MEMORY_SCOPE_AGENT);
}

__device__ __forceinline__ void zacc(f32x4 a[2][2]){
  #pragma unroll
  for (int i = 0; i < 2; ++i)
    #pragma unroll
    for (int j = 0; j < 2; ++j) a[i][j] = {0.f,0.f,0.f,0.f};
}

// Monotonic grid barrier: relaxed agent atomics only — NO cache-wiping fences.
// Payload correctness: all cross-block data uses agent-scope atomics (MALL-coherent);
// per-wave vmcnt(0) drain before arrive guarantees payload visible before counter bump.
__device__ __forceinline__ void gbar(unsigned* bc){
  asm volatile("s_waitcnt vmcnt(0) lgkmcnt(0)" ::: "memory");
  __syncthreads();
  if (threadIdx.x == 0) {
    unsigned prev = __hip_atomic_fetch_add(bc, 1u, __ATOMIC_RELAXED, __HIP_MEMORY_SCOPE_AGENT);
    unsigned need = (prev / NBLK)*NBLK + NBLK;
    while (__hip_atomic_load(bc, __ATOMIC_RELAXED, __HIP_MEMORY_SCOPE_AGENT) < need)
      __builtin_amdgcn_s_sleep(8);
  }
  __syncthreads();
}

// Double-buffered pipelined bf16 MFMA GEMM core. BK=64, one barrier per iter.
// LDS row stride 72 shorts. COHA: stage A via agent-coherent 8B atomic loads
// (activation panels crossing grid-barriers); B (weights) stays L2-cached.
template<int BM, int BN, bool COHA>
struct GemmPipe {
  static constexpr int LA = 72;
  static __device__ __forceinline__ bf16x8 ald(const short* p){
    if constexpr (COHA) {
      union { unsigned long long q[2]; bf16x8 v; } u;
      u.q[0] = coh_ld64(p); u.q[1] = coh_ld64(p + 4);
      return u.v;
    } else {
      return *(const bf16x8*)p;
    }
  }
  static __device__ __forceinline__ void run(short* Asb, short* Bsb,
      const short* __restrict__ A, const short* __restrict__ Bt,
      int lda, int ldb, int kBase, int nIter,
      int rowBase, int colBase, int tid, f32x4 acc[BM/32][BN/32])
  {
    constexpr int FI = BM/32, FJ = BN/32, ACH = BM/32, BCH = BN/32;
    const int lane = tid & 63, wave = tid >> 6;
    const int ml = lane & 15, kq = lane >> 4;
    const int wm = (wave >> 1)*(BM/2), wn = (wave & 1)*(BN/2);
    const int arow = (tid*ACH) >> 3, acol = ((tid*ACH) & 7)*8;
    const int brow = (tid*BCH) >> 3, bcol = ((tid*BCH) & 7)*8;
    const short* Ap = A + (size_t)(rowBase+arow)*lda + kBase + acol;
    const short* Bp = Bt + (size_t)(colBase+brow)*ldb + kBase + bcol;
    bf16x8 ar[ACH], br[BCH];
    #pragma unroll
    for (int c = 0; c < ACH; ++c) ar[c] = ald(Ap + c*8);
    #pragma unroll
    for (int c = 0; c < BCH; ++c) br[c] = *(const bf16x8*)(Bp + c*8);
    for (int i = 0; i < nIter; ++i) {
      short* Ab = Asb + (i&1)*(BM*LA);
      short* Bb = Bsb + (i&1)*(BN*LA);
      #pragma unroll
      for (int c = 0; c < ACH; ++c) *(bf16x8*)&Ab[arow*LA + acol + c*8] = ar[c];
      #pragma unroll
      for (int c = 0; c < BCH; ++c) *(bf16x8*)&Bb[brow*LA + bcol + c*8] = br[c];
      __syncthreads();
      if (i+1 < nIter) {
        const short* An = Ap + (size_t)(i+1)*64;
        const short* Bn = Bp + (size_t)(i+1)*64;
        #pragma unroll
        for (int c = 0; c < ACH; ++c) ar[c] = ald(An + c*8);
        #pragma unroll
        for (int c = 0; c < BCH; ++c) br[c] = *(const bf16x8*)(Bn + c*8);
      }
      #pragma unroll
      for (int kh = 0; kh < 2; ++kh) {
        bf16x8 af[FI], bfv[FJ];
        #pragma unroll
        for (int ii = 0; ii < FI; ++ii)
          af[ii] = *(const bf16x8*)&Ab[(wm + ii*16 + ml)*LA + kh*32 + kq*8];
        #pragma unroll
        for (int jj = 0; jj < FJ; ++jj)
          bfv[jj] = *(const bf16x8*)&Bb[(wn + jj*16 + ml)*LA + kh*32 + kq*8];
        #pragma unroll
        for (int ii = 0; ii < FI; ++ii)
          #pragma unroll
          for (int jj = 0; jj < FJ; ++jj)
            acc[ii][jj] = __builtin_amdgcn_mfma_f32_16x16x32_bf16(af[ii], bfv[jj], acc[ii][jj], 0,0,0);
      }
    }
    __syncthreads();
  }
};

// ---------------- role functions ----------------

// attention for b = 2*bid, 2*bid+1. Cross-block outputs via agent atomics.
__device__ __forceinline__ void attn_role(int bid, int tid, char* smem, int t,
    const short* __restrict__ enc_proj, const short* __restrict__ enc_out,
    const float* __restrict__ vvec, const int* __restrict__ mask,
    const int* __restrict__ targets, const short* __restrict__ embb,
    const short* __restrict__ hb, const short* __restrict__ wdecT,
    short* __restrict__ xcat0, short* __restrict__ predcat)
{
  const int b0 = bid*2;
  float* hbf = (float*)smem;                  // [2][512]
  float* dps = (float*)(smem + 4096);         // [ksel][b][512]
  float* vvf = (float*)(smem + 12288);        // [512]
  float* sc  = (float*)(smem + 14336);        // [2][64]
  float* wt  = (float*)(smem + 14848);        // [2][64]
  {
    union { unsigned long long q; bf16x4 v; } uh;
    uh.q = coh_ld64(&hb[(size_t)b0*HH + tid*4]);
    #pragma unroll
    for (int j = 0; j < 4; ++j) hbf[tid*4 + j] = bf2f(uh.v[j]);
    vvf[tid] = vvec[tid];
    vvf[256 + tid] = vvec[256 + tid];
  }
  __syncthreads();
  // dec_proj partials: unit=(b,h8), 2 threads per unit (k-halves of 256)
  {
    int unit = tid & 127, ksel = tid >> 7;
    int bb = unit >> 6, h8 = unit & 63;
    const short* wp = wdecT + (size_t)(ksel*256)*HH + h8*8;
    const float* hrow = hbf + bb*HH + ksel*256;
    float a[8] = {0.f,0.f,0.f,0.f,0.f,0.f,0.f,0.f};
    for (int k = 0; k < 256; ++k) {
      bf16x8 w8 = *(const bf16x8*)(wp + (size_t)k*HH);
      float x = hrow[k];
      #pragma unroll
      for (int j = 0; j < 8; ++j) a[j] += x * bf2f(w8[j]);
    }
    float* d = dps + (ksel*2 + bb)*HH + h8*8;
    #pragma unroll
    for (int j = 0; j < 8; ++j) d[j] = a[j];
  }
  __syncthreads();
  {   // combine k-halves
    int bb = tid >> 7, h0_ = (tid & 127)*4;
    f32x4 s0 = *(f32x4*)&dps[bb*HH + h0_];
    f32x4 s1 = *(f32x4*)&dps[(2 + bb)*HH + h0_];
    *(f32x4*)&dps[bb*HH + h0_] = s0 + s1;
  }
  __syncthreads();
  // scores: unit=(b,s), 2 lanes per unit (h-halves of 256)
  {
    int u = tid >> 1, khalf = tid & 1;
    int bb = u >> 6, s = u & 63;
    const short* ep = enc_proj + ((size_t)(b0+bb)*SS + s)*HH + khalf*256;
    const float* dpp = dps + bb*HH + khalf*256;
    const float* vp  = vvf + khalf*256;
    float accv = 0.f;
    for (int hc = 0; hc < 32; ++hc) {
      bf16x8 e8 = *(const bf16x8*)(ep + hc*8);
      f32x4 d0 = *(const f32x4*)(dpp + hc*8);
      f32x4 d1 = *(const f32x4*)(dpp + hc*8 + 4);
      f32x4 v0 = *(const f32x4*)(vp + hc*8);
      f32x4 v1 = *(const f32x4*)(vp + hc*8 + 4);
      #pragma unroll
      for (int j = 0; j < 4; ++j) accv += v0[j]*tanh_fast(d0[j] + bf2f(e8[j]));
      #pragma unroll
      for (int j = 0; j < 4; ++j) accv += v1[j]*tanh_fast(d1[j] + bf2f(e8[4+j]));
    }
    accv += __shfl_xor(accv, 1, 64);
    if (khalf == 0) sc[bb*64 + s] = accv;
  }
  __syncthreads();
  if (tid < 128) {   // masked softmax: wave0 -> b0, wave1 -> b1
    int bb = tid >> 6, s = tid & 63;
    int valid = mask[(b0+bb)*SS + s];
    float x = valid ? sc[bb*64 + s] : -INFINITY;
    float mx = x;
    #pragma unroll
    for (int off = 32; off; off >>= 1) mx = fmaxf(mx, __shfl_xor(mx, off, 64));
    float e = valid ? __expf(x - mx) : 0.f;
    float sum = e;
    #pragma unroll
    for (int off = 32; off; off >>= 1) sum += __shfl_xor(sum, off, 64);
    wt[bb*64 + s] = e / sum;
  }
  __syncthreads();
  {   // context
    int bb = tid >> 7, d0 = (tid & 127)*8;
    const short* eob = enc_out + (size_t)(b0+bb)*SS*DENC + d0;
    float ca[8] = {0.f,0.f,0.f,0.f,0.f,0.f,0.f,0.f};
    for (int s = 0; s < SS; ++s) {
      float w = wt[bb*64 + s];
      bf16x8 e8 = *(const bf16x8*)(eob + (size_t)s*DENC);
      #pragma unroll
      for (int j = 0; j < 8; ++j) ca[j] += w * bf2f(e8[j]);
    }
    union { bf16x8 v; unsigned long long q[2]; } uc;
    #pragma unroll
    for (int j = 0; j < 8; ++j) uc.v[j] = f2bf(ca[j]);
    int b_ = b0 + bb;
    coh_st64(&xcat0[(size_t)b_*XW0 + EE + d0], uc.q[0]);
    coh_st64(&xcat0[(size_t)b_*XW0 + EE + d0 + 4], uc.q[1]);
    coh_st64(&predcat[(size_t)b_*PW + HH + d0], uc.q[0]);
    coh_st64(&predcat[(size_t)b_*PW + HH + d0 + 4], uc.q[1]);
  }
  if (tid < 128) {   // pred emb (x_emb for this step's pred concat)
    int bb = tid >> 6, e0 = (tid & 63)*4;
    int b_ = b0 + bb;
    int tok = (t == 0) ? 2 : targets[b_*TT + t - 1];
    union { short s[4]; unsigned long long q; } u;
    #pragma unroll
    for (int j = 0; j < 4; ++j) u.s[j] = embb[tok*EE + e0 + j];
    coh_st64(&predcat[(size_t)b_*PW + HH + DENC + e0], u.q);
  }
}

// fallback-only: full out GEMM
__device__ __forceinline__ void out_role(int idx, int tid, char* smem,
    const short* __restrict__ predprev, const short* __restrict__ wout,
    const float* __restrict__ b_out, float* __restrict__ out, int t)
{
  short* As = (short*)smem;
  short* Bs = (short*)(smem + 18432);
  const int rowBase = (idx >> 1)*64, colBase = (idx & 1)*64;
  f32x4 acc[2][2];
  zacc(acc);
  GemmPipe<64,64,false>::run(As, Bs, predprev, wout, PW, PW, 0, PW/64, rowBase, colBase, tid, acc);
  const int lane = tid & 63, wave = tid >> 6, ml = lane & 15, kq = lane >> 4;
  const int wm = (wave >> 1)*32, wn = (wave & 1)*32;
  #pragma unroll
  for (int ii = 0; ii < 2; ++ii)
    #pragma unroll
    for (int jj = 0; jj < 2; ++jj) {
      int n = colBase + wn + jj*16 + ml;
      float bv = b_out[n];
      #pragma unroll
      for (int r2 = 0; r2 < 4; ++r2) {
        int m = rowBase + wm + ii*16 + kq*4 + r2;
        out[(size_t)m*(TT*VV) + (size_t)(t-1)*VV + n] = acc[ii][jj][r2] + bv;
      }
    }
}

// LSTM cell epilogue from register accumulator; h outputs via agent atomics.
__device__ __forceinline__ void gates_epi(int tid, int rowBase, int colBase,
    char* smem, f32x4 acc[2][2], const float* __restrict__ bias,
    float* __restrict__ cb,
    short* __restrict__ d1, int ld1, short* __restrict__ d2, int ld2,
    short* __restrict__ d3)
{
  const int lane = tid & 63, wave = tid >> 6, ml = lane & 15, kq = lane >> 4;
  const int wm = (wave >> 1)*32, wn = (wave & 1)*32;
  float* Ct = (float*)smem;                    // 64*68*4 = 17408
  short* hs = (short*)(smem + 18432);          // [64][16] staged h
  float bj0 = bias[colBase + wn + ml];
  float bj1 = bias[colBase + wn + 16 + ml];
  #pragma unroll
  for (int ii = 0; ii < 2; ++ii)
    #pragma unroll
    for (int jj = 0; jj < 2; ++jj)
      #pragma unroll
      for (int r2 = 0; r2 < 4; ++r2)
        Ct[(wm + ii*16 + kq*4 + r2)*68 + wn + jj*16 + ml] = acc[ii][jj][r2] + (jj ? bj1 : bj0);
  __syncthreads();
  #pragma unroll
  for (int kk = 0; kk < 4; ++kk) {
    int cidx = tid + kk*256;
    int m = cidx >> 4, hl = cidx & 15;
    float4 gv = *(float4*)&Ct[m*68 + hl*4];    // i,f,g,o
    int b_ = rowBase + m, h_ = (colBase >> 2) + hl;
    float cp = cb[b_*HH + h_];                 // c-state: same block every step -> plain
    float cn = sigf(gv.y)*cp + sigf(gv.x)*tanhf(gv.z);
    float hn = sigf(gv.w)*tanhf(cn);
    cb[b_*HH + h_] = cn;
    hs[m*16 + hl] = f2bf(hn);
  }
  __syncthreads();
  {
    int m = tid >> 2, c4 = (tid & 3)*4;
    union { short s[4]; unsigned long long q; } u;
    #pragma unroll
    for (int j = 0; j < 4; ++j) u.s[j] = hs[m*16 + c4 + j];
    int b_ = rowBase + m, hbase = (colBase >> 2) + c4;
    coh_st64(d1 + (size_t)b_*ld1 + hbase, u.q);
    coh_st64(d2 + (size_t)b_*ld2 + hbase, u.q);
    if (d3) coh_st64(d3 + (size_t)b_*HH + hbase, u.q);
  }
}

// write emb(token for step t+1) into next xcat0 buffer: 64 b-rows from rowBase
__device__ __forceinline__ void emb_prewrite(int rowBase, int tid,
    short* __restrict__ xc0n, const int* __restrict__ targets,
    const short* __restrict__ embb, int t)
{
  int b_ = rowBase + (tid >> 2);
  int tok = targets[b_*TT + t];
  const short* src = embb + tok*EE + (tid & 3)*64;
  short* dst = xc0n + (size_t)b_*XW0 + (tid & 3)*64;
  #pragma unroll
  for (int j = 0; j < 8; ++j) {
    union { bf16x8 v; unsigned long long q[2]; } u;
    u.v = *(const bf16x8*)(src + j*8);
    coh_st64(dst + j*8, u.q[0]);
    coh_st64(dst + j*8 + 4, u.q[1]);
  }
}

// ---------------- persistent cooperative decode kernel ----------------
// 768 blocks x 256 thr (3/CU). Per step:
//  ph1: attn(0-255) || G0 partial K={emb,h0prev} (256-511) || G1 partial K=h1prev (512-767)
//  ph2: G0 finish K=ctx + LSTM0 || out-GEMM halves (32 G1 blocks) || emb prewrite (attn blocks)
//  ph3: G1 finish K=h0n + LSTM1 || out reduce+write (16 lead blocks)
// Accumulators stay in VGPRs across barriers (no partial-matrix traffic).
__global__ __launch_bounds__(256, 3)
void decode_persist(
    const short* __restrict__ enc_proj, const short* __restrict__ enc_out,
    const float* __restrict__ vvec, const int* __restrict__ mask,
    const int* __restrict__ targets, const short* __restrict__ embb,
    short* __restrict__ hb, const short* __restrict__ wdecT,
    short* __restrict__ xc0a, short* __restrict__ xc0b,
    short* __restrict__ xc1a, short* __restrict__ xc1b,
    short* __restrict__ pca, short* __restrict__ pcb,
    const short* __restrict__ wcat0, const short* __restrict__ wcat1,
    const float* __restrict__ bias0, const float* __restrict__ bias1,
    float* __restrict__ cbuf, float* __restrict__ Pout,
    const short* __restrict__ wout, const float* __restrict__ b_out,
    float* __restrict__ out, unsigned* __restrict__ bc)
{
  __shared__ __align__(16) char smem[36864];
  const int bid = blockIdx.x, tid = threadIdx.x;
  const bool isA  = bid < 256;
  const bool isG0 = bid >= 256 && bid < 512;
  const bool isG1 = bid >= 512;
  const int gidx = isG0 ? (bid - 256) : (bid - 512);
  const int rowBase = (gidx >> 5)*64, colBase = (gidx & 31)*64;
  const bool outHalf = isG1 && gidx < 32;
  const bool outLead = isG1 && gidx < 16;
  const int oIdx = gidx & 15;
  const int oRow = (oIdx >> 1)*64, oCol = (oIdx & 1)*64;
  short* As = (short*)smem;
  short* Bs = (short*)(smem + 18432);
  f32x4 acc[2][2];    // gates accumulator (lives across ph1->ph2/ph3)
  f32x4 accO[2][2];   // out-half accumulator (lives across ph2->ph3)

  #pragma unroll 1
  for (int t = 0; t <= TT; ++t) {
    short* xc0c = (t & 1) ? xc0b : xc0a;
    short* xc0n = (t & 1) ? xc0a : xc0b;
    short* xc1c = (t & 1) ? xc1b : xc1a;
    short* xc1n = (t & 1) ? xc1a : xc1b;
    short* pcc  = (t & 1) ? pcb  : pca;
    short* pcn  = (t & 1) ? pca  : pcb;
    // ---------- phase 1 ----------
    if (t < TT) {
      if (isA) {
        attn_role(bid, tid, smem, t, enc_proj, enc_out, vvec, mask, targets,
                  embb, hb, wdecT, xc0c, pcc);
      } else if (isG0) {
        zacc(acc);
        GemmPipe<64,64,true>::run(As, Bs, xc0c, wcat0, XW0, XW0, 0,    4, rowBase, colBase, tid, acc);
        GemmPipe<64,64,true>::run(As, Bs, xc0c, wcat0, XW0, XW0, 1280, 8, rowBase, colBase, tid, acc);
      } else {
        zacc(acc);
        GemmPipe<64,64,true>::run(As, Bs, xc1c, wcat1, XW1, XW1, 512, 8, rowBase, colBase, tid, acc);
      }
    }
    gbar(bc);
    // ---------- phase 2 ----------
    if (isG0) {
      if (t < TT) {
        GemmPipe<64,64,true>::run(As, Bs, xc0c, wcat0, XW0, XW0, 256, 16, rowBase, colBase, tid, acc);
        gates_epi(tid, rowBase, colBase, smem, acc, bias0, cbuf,
                  xc1c, XW1, xc0n + EE + DENC, XW0, (short*)nullptr);
      }
    } else if (outHalf) {
      if (t >= 1) {
        zacc(accO);
        GemmPipe<64,64,true>::run(As, Bs, pcn, wout, PW, PW, outLead ? 0 : 896, 14,
                                  oRow, oCol, tid, accO);
        if (!outLead) {
          const int lane = tid & 63, wave = tid >> 6, ml = lane & 15, kq = lane >> 4;
          const int wm = (wave >> 1)*32, wn = (wave & 1)*32;
          float* Pt = Pout + (size_t)oIdx*4096;
          #pragma unroll
          for (int ii = 0; ii < 2; ++ii)
            #pragma unroll
            for (int jj = 0; jj < 2; ++jj)
              #pragma unroll
              for (int r2 = 0; r2 < 4; ++r2)
                coh_stf(&Pt[(wm+ii*16+kq*4+r2)*64 + wn+jj*16+ml], accO[ii][jj][r2]);
        }
      }
    } else if (isA && bid < 8) {
      if (t + 1 < TT) emb_prewrite(bid*64, tid, xc0n, targets, embb, t);
    }
    gbar(bc);
    // ---------- phase 3 ----------
    if (isG1 && t < TT) {
      GemmPipe<64,64,true>::run(As, Bs, xc1c, wcat1, XW1, XW1, 0, 8, rowBase, colBase, tid, acc);
      gates_epi(tid, rowBase, colBase, smem, acc, bias1, cbuf + BH,
                xc1n + HH, XW1, pcc, PW, hb);
    }
    if (outLead && t >= 1) {
      const int lane = tid & 63, wave = tid >> 6, ml = lane & 15, kq = lane >> 4;
      const int wm = (wave >> 1)*32, wn = (wave & 1)*32;
      const float* Pt = Pout + (size_t)oIdx*4096;
      #pragma unroll
      for (int ii = 0; ii < 2; ++ii)
        #pragma unroll
        for (int jj = 0; jj < 2; ++jj) {
          int n = oCol + wn + jj*16 + ml;
          float bv = b_out[n];
          #pragma unroll
          for (int r2 = 0; r2 < 4; ++r2) {
            int m = oRow + wm + ii*16 + kq*4 + r2;
            float ph = coh_ldf(&Pt[(wm+ii*16+kq*4+r2)*64 + wn+jj*16+ml]);
            out[(size_t)m*(TT*VV) + (size_t)(t-1)*VV + n] = accO[ii][jj][r2] + ph + bv;
          }
        }
    }
    if (t == TT) break;
    gbar(bc);
  }
}

// ---------------- fallback (original 3-kernel pipeline) ----------------

__global__ __launch_bounds__(256)
void gates_fused(const short* __restrict__ A, const short* __restrict__ W,
                 const float* __restrict__ bias, float* __restrict__ cb,
                 short* __restrict__ d1, short* __restrict__ d2, short* __restrict__ d3,
                 int K, int layer)
{
  __shared__ __align__(16) char smem[36864];
  short* As = (short*)smem;
  short* Bs = (short*)(smem + 18432);
  const int tid = threadIdx.x;
  const int rowBase = blockIdx.y*64, colBase = blockIdx.x*64;
  f32x4 acc[2][2];
  zacc(acc);
  GemmPipe<64,64,false>::run(As, Bs, A, W, K, K, 0, K >> 6, rowBase, colBase, tid, acc);
  const int lane = tid & 63, wave = tid >> 6, ml = lane & 15, kq = lane >> 4;
  const int wm = (wave >> 1)*32, wn = (wave & 1)*32;
  float* Ct = (float*)smem;
  float bj0 = bias[colBase + wn + ml];
  float bj1 = bias[colBase + wn + 16 + ml];
  #pragma unroll
  for (int ii = 0; ii < 2; ++ii)
    #pragma unroll
    for (int jj = 0; jj < 2; ++jj)
      #pragma unroll
      for (int r2 = 0; r2 < 4; ++r2)
        Ct[(wm + ii*16 + kq*4 + r2)*68 + wn + jj*16 + ml] = acc[ii][jj][r2] + (jj ? bj1 : bj0);
  __syncthreads();
  #pragma unroll
  for (int kk = 0; kk < 4; ++kk) {
    int cidx = tid + kk*256;
    int m = cidx >> 4, hl = cidx & 15;
    float4 gv = *(float4*)&Ct[m*68 + hl*4];
    int b_ = rowBase + m, h_ = (colBase >> 2) + hl;
    float cp = cb[b_*HH + h_];
    float cn = sigf(gv.y)*cp + sigf(gv.x)*tanhf(gv.z);
    float hn = sigf(gv.w)*tanhf(cn);
    cb[b_*HH + h_] = cn;
    short hb16 = f2bf(hn);
    if (layer == 0) {
      d1[(size_t)b_*XW1 + h_] = hb16;
      d2[(size_t)b_*XW0 + h_] = hb16;
    } else {
      d1[(size_t)b_*XW1 + h_] = hb16;
      d2[(size_t)b_*PW  + h_] = hb16;
      d3[(size_t)b_*HH  + h_] = hb16;
    }
  }
}

__global__ __launch_bounds__(256)
void attn_out(const short* __restrict__ enc_proj, const short* __restrict__ enc_out,
              const float* __restrict__ vvec, const int* __restrict__ mask,
              const int* __restrict__ targets, const short* __restrict__ embb,
              const short* __restrict__ hb, const short* __restrict__ wdecT,
              short* __restrict__ xcat0, short* __restrict__ predcat,
              const short* __restrict__ predprev, const short* __restrict__ wout,
              const float* __restrict__ b_out, float* __restrict__ out, int t)
{
  __shared__ __align__(16) char smem[36864];
  const int tid = threadIdx.x;
  if (blockIdx.x >= 256) {
    if (t == 0) return;
    out_role(blockIdx.x - 256, tid, smem, predprev, wout, b_out, out, t);
    return;
  }
  if (t >= TT) return;
  attn_role(blockIdx.x, tid, smem, t, enc_proj, enc_out, vvec, mask, targets,
            embb, hb, wdecT, xcat0, predcat);
  #pragma unroll
  for (int bb = 0; bb < 2; ++bb) {   // fallback: write xcat0 emb directly
    int b_ = blockIdx.x*2 + bb;
    int tok = (t == 0) ? 2 : targets[b_*TT + t - 1];
    xcat0[(size_t)b_*XW0 + tid] = embb[tok*EE + tid];
  }
}

// enc_proj = enc_out @ W_enc.T (M=32768, N=512, K=1024), bf16 out.
__global__ __launch_bounds__(256)
void enc_gemm(short* __restrict__ C, const short* __restrict__ A, const short* __restrict__ Bt,
              int K, int ldc)
{
  __shared__ __align__(16) char smem[55296];
  short* As = (short*)smem;
  short* Bs = (short*)(smem + 18432);
  const int tid = threadIdx.x;
  const int rowBase = blockIdx.y*64, colBase = blockIdx.x*128;
  f32x4 acc[2][4];
  #pragma unroll
  for (int i = 0; i < 2; ++i)
    #pragma unroll
    for (int j = 0; j < 4; ++j) acc[i][j] = {0.f,0.f,0.f,0.f};
  GemmPipe<64,128,false>::run(As, Bs, A, Bt, K, K, 0, K >> 6, rowBase, colBase, tid, acc);
  const int lane = tid & 63, wave = tid >> 6, ml = lane & 15, kq = lane >> 4;
  const int wm = (wave >> 1)*32, wn = (wave & 1)*64;
  #pragma unroll
  for (int ii = 0; ii < 2; ++ii)
    #pragma unroll
    for (int jj = 0; jj < 4; ++jj) {
      int n = colBase + wn + jj*16 + ml;
      #pragma unroll
      for (int r2 = 0; r2 < 4; ++r2) {
        int m = rowBase + wm + ii*16 + kq*4 + r2;
        C[(size_t)m*ldc + n] = f2bf(acc[ii][jj][r2]);
      }
    }
}

__global__ __launch_bounds__(256)
void build_wcat_bf(short* __restrict__ wcat0, short* __restrict__ wcat1,
                   const float* __restrict__ wih0, const float* __restrict__ whh0,
                   const float* __restrict__ wih1, const float* __restrict__ whh1)
{
  int idx = blockIdx.x*256 + threadIdx.x;
  const int N0 = G4H*XW0;
  if (idx < N0) {
    int n = idx / XW0, k = idx % XW0;
    int row = (n & 3)*HH + (n >> 2);
    float v = (k < EE+DENC) ? wih0[(size_t)row*(EE+DENC) + k] : whh0[(size_t)row*HH + (k - (EE+DENC))];
    wcat0[idx] = f2bf(v);
  } else {
    int j = idx - N0;
    int n = j / XW1, k = j % XW1;
    int row = (n & 3)*HH + (n >> 2);
    float v = (k < HH) ? wih1[(size_t)row*HH + k] : whh1[(size_t)row*HH + (k - HH)];
    wcat1[j] = f2bf(v);
  }
}

__global__ __launch_bounds__(256)
void cvt_encout(short* __restrict__ dst, const float* __restrict__ src)
{
  size_t i8 = ((size_t)blockIdx.x*256 + threadIdx.x)*8;
  float4 a = *(const float4*)&src[i8];
  float4 b = *(const float4*)&src[i8+4];
  bf16x8 o;
  o[0]=f2bf(a.x); o[1]=f2bf(a.y); o[2]=f2bf(a.z); o[3]=f2bf(a.w);
  o[4]=f2bf(b.x); o[5]=f2bf(b.y); o[6]=f2bf(b.z); o[7]=f2bf(b.w);
  *(bf16x8*)&dst[i8] = o;
}

__global__ __launch_bounds__(256)
void prep_misc(float* __restrict__ cbuf, short* __restrict__ xcat0a, short* __restrict__ xcat1a,
               short* __restrict__ hb, short* __restrict__ wdecT, short* __restrict__ wenc,
               short* __restrict__ wout, short* __restrict__ embb,
               float* __restrict__ bias0i, float* __restrict__ bias1i,
               unsigned* __restrict__ bcz,
               const float* __restrict__ c0, const float* __restrict__ h0,
               const float* __restrict__ W_dec, const float* __restrict__ W_enc,
               const float* __restrict__ W_out, const float* __restrict__ emb,
               const float* __restrict__ b_ih0, const float* __restrict__ b_hh0,
               const float* __restrict__ b_ih1, const float* __restrict__ b_hh1)
{
  int idx = blockIdx.x*256 + threadIdx.x;
  if (idx < 524288) { cbuf[idx] = c0[idx]; return; }
  idx -= 524288;
  if (idx < 262144) {
    int b = idx >> 9, h = idx & 511;
    xcat0a[(size_t)b*XW0 + EE + DENC + h] = f2bf(h0[idx]);
    return;
  }
  idx -= 262144;
  if (idx < 262144) {
    int b = idx >> 9, h = idx & 511;
    short v = f2bf(h0[BH + idx]);
    xcat1a[(size_t)b*XW1 + HH + h] = v;
    hb[idx] = v;
    return;
  }
  idx -= 262144;
  if (idx < 262144) {                           // wdecT[k][n] = W_dec[n][k]
    int k = idx >> 9, n = idx & 511;
    wdecT[idx] = f2bf(W_dec[(size_t)n*HH + k]);
    return;
  }
  idx -= 262144;
  if (idx < 524288) { wenc[idx] = f2bf(W_enc[idx]); return; }
  idx -= 524288;
  if (idx < 229376) { wout[idx] = f2bf(W_out[idx]); return; }
  idx -= 229376;
  if (idx < 32768)  { embb[idx] = f2bf(emb[idx]); return; }
  idx -= 32768;
  if (idx < 2048) {
    int row = (idx & 3)*HH + (idx >> 2);
    bias0i[idx] = b_ih0[row] + b_hh0[row];
    return;
  }
  idx -= 2048;
  if (idx < 2048) {
    int row = (idx & 3)*HH + (idx >> 2);
    bias1i[idx] = b_ih1[row] + b_hh1[row];
    return;
  }
  idx -= 2048;
  if (idx < 131072) {                           // emb(t=0) = emb[EOS=2] into xcat0a
    int b = idx >> 8, e = idx & 255;
    xcat0a[(size_t)b*XW0 + e] = f2bf(emb[2*EE + e]);
    return;
  }
  idx -= 131072;
  if (idx == 0) *bcz = 0;                       // grid-barrier counter
}

extern "C" void kernel_launch(void* const* d_in, const int* in_sizes, int n_in,
                              void* d_out, int out_size, void* d_ws, size_t ws_size,
                              hipStream_t stream) {
  const float* enc_out = (const float*)d_in[0];
  const float* h0      = (const float*)d_in[1];
  const float* c0      = (const float*)d_in[2];
  const int*   targets = (const int*)d_in[3];
  const int*   mask    = (const int*)d_in[4];
  const float* emb     = (const float*)d_in[5];
  const float* W_enc   = (const float*)d_in[6];
  const float* W_dec   = (const float*)d_in[7];
  const float* v       = (const float*)d_in[8];
  const float* b_ih0   = (const float*)d_in[11];
  const float* b_hh0   = (const float*)d_in[12];
  const float* b_ih1   = (const float*)d_in[15];
  const float* b_hh1   = (const float*)d_in[16];
  const float* b_out   = (const float*)d_in[18];
  float* out = (float*)d_out;

  char* ws = (char*)d_ws;
  size_t o = 0;
  short* enc_out_bf = (short*)(ws + o); o += (size_t)BB*SS*DENC*2;
  short* enc_proj_bf= (short*)(ws + o); o += (size_t)BB*SS*HH*2;
  short* wcat0i     = (short*)(ws + o); o += (size_t)G4H*XW0*2;
  short* wcat1i     = (short*)(ws + o); o += (size_t)G4H*XW1*2;
  short* wdecT      = (short*)(ws + o); o += (size_t)HH*HH*2;
  short* wenc_bf    = (short*)(ws + o); o += (size_t)HH*DENC*2;
  short* wout_bf    = (short*)(ws + o); o += (size_t)VV*PW*2;
  short* emb_bf     = (short*)(ws + o); o += (size_t)VV*EE*2;
  short* xcat0a     = (short*)(ws + o); o += (size_t)BB*XW0*2;
  short* xcat0b     = (short*)(ws + o); o += (size_t)BB*XW0*2;
  short* xcat1a     = (short*)(ws + o); o += (size_t)BB*XW1*2;
  short* xcat1b     = (short*)(ws + o); o += (size_t)BB*XW1*2;
  short* predcata   = (short*)(ws + o); o += (size_t)BB*PW*2;
  short* predcatb   = (short*)(ws + o); o += (size_t)BB*PW*2;
  short* hb         = (short*)(ws + o); o += (size_t)BH*2;
  float* cbuf       = (float*)(ws + o); o += (size_t)2*BH*4;
  float* bias0i     = (float*)(ws + o); o += (size_t)G4H*4;
  float* bias1i     = (float*)(ws + o); o += (size_t)G4H*4;
  float* Pout       = (float*)(ws + o); o += (size_t)16*4096*4;
  unsigned* barcnt  = (unsigned*)(ws + o); o += 64;
  (void)ws_size; (void)in_sizes; (void)n_in; (void)out_size;

  cvt_encout<<<16384, 256, 0, stream>>>(enc_out_bf, enc_out);
  build_wcat_bf<<<22528, 256, 0, stream>>>(wcat0i, wcat1i,
      (const float*)d_in[9], (const float*)d_in[10], (const float*)d_in[13], (const float*)d_in[14]);
  prep_misc<<<8721, 256, 0, stream>>>(cbuf, xcat0a, xcat1a, hb, wdecT, wenc_bf, wout_bf, emb_bf,
      bias0i, bias1i, barcnt, c0, h0, W_dec, W_enc, (const float*)d_in[17], emb,
      b_ih0, b_hh0, b_ih1, b_hh1);
  enc_gemm<<<dim3(HH/128, (BB*SS)/64), 256, 0, stream>>>(
      enc_proj_bf, enc_out_bf, wenc_bf, DENC, HH);

  void* kargs[] = {
    (void*)&enc_proj_bf, (void*)&enc_out_bf, (void*)&v, (void*)&mask,
    (void*)&targets, (void*)&emb_bf, (void*)&hb, (void*)&wdecT,
    (void*)&xcat0a, (void*)&xcat0b, (void*)&xcat1a, (void*)&xcat1b,
    (void*)&predcata, (void*)&predcatb, (void*)&wcat0i, (void*)&wcat1i,
    (void*)&bias0i, (void*)&bias1i, (void*)&cbuf, (void*)&Pout,
    (void*)&wout_bf, (void*)&b_out, (void*)&out, (void*)&barcnt
  };
  hipError_t cerr = hipLaunchCooperativeKernel((void*)decode_persist,
      dim3(NBLK), dim3(256), kargs, 0, stream);
  if (cerr != hipSuccess) {
    (void)hipGetLastError();   // clear sticky error; fall back to 3-kernel loop
    short* xc0[2] = {xcat0a, xcat0b};
    short* xc1[2] = {xcat1a, xcat1b};
    short* pc[2]  = {predcata, predcatb};
    for (int t = 0; t < TT; ++t) {
      attn_out<<<272, 256, 0, stream>>>(enc_proj_bf, enc_out_bf, v, mask, targets, emb_bf,
          hb, wdecT, xc0[t&1], pc[t&1], pc[(t+1)&1], wout_bf, b_out, out, t);
      gates_fused<<<dim3(G4H/64, BB/64), 256, 0, stream>>>(
          xc0[t&1], wcat0i, bias0i, cbuf, xc1[t&1], xc0[(t+1)&1] + EE + DENC, (short*)nullptr, XW0, 0);
      gates_fused<<<dim3(G4H/64, BB/64), 256, 0, stream>>>(
          xc1[t&1], wcat1i, bias1i, cbuf + BH, xc1[(t+1)&1] + HH, pc[t&1], hb, XW1, 1);
    }
    attn_out<<<272, 256, 0, stream>>>(enc_proj_bf, enc_out_bf, v, mask, targets, emb_bf,
        hb, wdecT, xc0[0], pc[0], pc[1], wout_bf, b_out, out, TT);
  }
}

// Round 4
// 3107.657 us; speedup vs baseline: 7.3916x; 2.1916x over previous
//
#include <hip/hip_runtime.h>
#include <math.h>

#define BB 512
#define SS 64
#define TT 32
#define VV 128
#define EE 256
#define HH 512
#define DENC 1024
#define BH (BB*HH)
#define XW0 1792   // E + DENC + H
#define XW1 1024   // H + H
#define PW  1792   // H + DENC + E
#define G4H 2048   // 4*H

typedef __attribute__((ext_vector_type(8))) short bf16x8;
typedef __attribute__((ext_vector_type(4))) short bf16x4;
typedef __attribute__((ext_vector_type(4))) float f32x4;

__device__ __forceinline__ float sigf(float x){ return 1.f/(1.f+expf(-x)); }
__device__ __forceinline__ float bf2f(short s){
  return __uint_as_float(((unsigned)(unsigned short)s) << 16);
}
__device__ __forceinline__ short f2bf(float f){
  unsigned u = __float_as_uint(f);
  return (short)((u + 0x7FFF + ((u>>16)&1)) >> 16);   // RNE
}
__device__ __forceinline__ float tanh_fast(float x){
  x = fminf(fmaxf(x, -15.f), 15.f);
  float e = __expf(2.f*x);
  return (e - 1.f) / (e + 1.f);
}

// Double-buffered pipelined bf16 MFMA GEMM core. BK=64, one barrier per iter.
// LDS row stride 72 shorts (2-way bank aliasing only). K multiple of 64.
// Wave w computes tile (BM/2)x(BN/2) at wm=(w>>1)*(BM/2), wn=(w&1)*(BN/2).
template<int BM, int BN>
struct GemmPipe {
  static constexpr int LA = 72;
  static __device__ __forceinline__ void run(short* Asb, short* Bsb,
      const short* __restrict__ A, const short* __restrict__ Bt,
      int lda, int ldb, int kBase, int nIter,
      int rowBase, int colBase, int tid, f32x4 acc[BM/32][BN/32])
  {
    constexpr int FI = BM/32, FJ = BN/32, ACH = BM/32, BCH = BN/32;
    const int lane = tid & 63, wave = tid >> 6;
    const int ml = lane & 15, kq = lane >> 4;
    const int wm = (wave >> 1)*(BM/2), wn = (wave & 1)*(BN/2);
    const int arow = (tid*ACH) >> 3, acol = ((tid*ACH) & 7)*8;
    const int brow = (tid*BCH) >> 3, bcol = ((tid*BCH) & 7)*8;
    const short* Ap = A + (size_t)(rowBase+arow)*lda + kBase + acol;
    const short* Bp = Bt + (size_t)(colBase+brow)*ldb + kBase + bcol;
    bf16x8 ar[ACH], br[BCH];
    #pragma unroll
    for (int c = 0; c < ACH; ++c) ar[c] = *(const bf16x8*)(Ap + c*8);
    #pragma unroll
    for (int c = 0; c < BCH; ++c) br[c] = *(const bf16x8*)(Bp + c*8);
    for (int i = 0; i < nIter; ++i) {
      short* Ab = Asb + (i&1)*(BM*LA);
      short* Bb = Bsb + (i&1)*(BN*LA);
      #pragma unroll
      for (int c = 0; c < ACH; ++c) *(bf16x8*)&Ab[arow*LA + acol + c*8] = ar[c];
      #pragma unroll
      for (int c = 0; c < BCH; ++c) *(bf16x8*)&Bb[brow*LA + bcol + c*8] = br[c];
      __syncthreads();
      if (i+1 < nIter) {
        const short* An = Ap + (size_t)(i+1)*64;
        const short* Bn = Bp + (size_t)(i+1)*64;
        #pragma unroll
        for (int c = 0; c < ACH; ++c) ar[c] = *(const bf16x8*)(An + c*8);
        #pragma unroll
        for (int c = 0; c < BCH; ++c) br[c] = *(const bf16x8*)(Bn + c*8);
      }
      #pragma unroll
      for (int kh = 0; kh < 2; ++kh) {
        bf16x8 af[FI], bfv[FJ];
        #pragma unroll
        for (int ii = 0; ii < FI; ++ii)
          af[ii] = *(const bf16x8*)&Ab[(wm + ii*16 + ml)*LA + kh*32 + kq*8];
        #pragma unroll
        for (int jj = 0; jj < FJ; ++jj)
          bfv[jj] = *(const bf16x8*)&Bb[(wn + jj*16 + ml)*LA + kh*32 + kq*8];
        #pragma unroll
        for (int ii = 0; ii < FI; ++ii)
          #pragma unroll
          for (int jj = 0; jj < FJ; ++jj)
            acc[ii][jj] = __builtin_amdgcn_mfma_f32_16x16x32_bf16(af[ii], bfv[jj], acc[ii][jj], 0,0,0);
      }
    }
    __syncthreads();
  }
};

// out GEMM for one 64x64 tile: out[:, t-1, :] = predprev @ wout.T + b_out
__device__ __forceinline__ void out_role(int idx, int tid, char* smem,
    const short* __restrict__ predprev, const short* __restrict__ wout,
    const float* __restrict__ b_out, float* __restrict__ out, int t)
{
  short* As = (short*)smem;
  short* Bs = (short*)(smem + 18432);
  const int rowBase = (idx >> 1)*64, colBase = (idx & 1)*64;
  f32x4 acc[2][2];
  #pragma unroll
  for (int i = 0; i < 2; ++i)
    #pragma unroll
    for (int j = 0; j < 2; ++j) acc[i][j] = {0.f,0.f,0.f,0.f};
  GemmPipe<64,64>::run(As, Bs, predprev, wout, PW, PW, 0, PW/64, rowBase, colBase, tid, acc);
  const int lane = tid & 63, wave = tid >> 6, ml = lane & 15, kq = lane >> 4;
  const int wm = (wave >> 1)*32, wn = (wave & 1)*32;
  #pragma unroll
  for (int ii = 0; ii < 2; ++ii)
    #pragma unroll
    for (int jj = 0; jj < 2; ++jj) {
      int n = colBase + wn + jj*16 + ml;
      float bv = b_out[n];
      #pragma unroll
      for (int r2 = 0; r2 < 4; ++r2) {
        int m = rowBase + wm + ii*16 + kq*4 + r2;
        out[(size_t)m*(TT*VV) + (size_t)(t-1)*VV + n] = acc[ii][jj][r2] + bv;
      }
    }
}

// One batch row per 128-thread block. Bit-identical math to the 2-row/256-thread
// version (same unit splits: dec_proj k-halves, score h-halves, ctx s-serial).
// 512 blocks -> 2 independent blocks/CU: serial phases of the two rows interleave.
__global__ __launch_bounds__(128)
void attn_row(const short* __restrict__ enc_proj, const short* __restrict__ enc_out,
              const float* __restrict__ vvec, const int* __restrict__ mask,
              const int* __restrict__ targets, const short* __restrict__ embb,
              const short* __restrict__ hb, const short* __restrict__ wdecT,
              short* __restrict__ xcat0, short* __restrict__ predcat, int t)
{
  __shared__ float hbf[512];
  __shared__ float dps[2][512];
  __shared__ float vvf[512];
  __shared__ float sc[64];
  __shared__ float wt[64];
  const int tid = threadIdx.x;
  const int b = blockIdx.x;
  {
    bf16x4 h4 = *(const bf16x4*)&hb[(size_t)b*HH + tid*4];
    #pragma unroll
    for (int j = 0; j < 4; ++j) hbf[tid*4 + j] = bf2f(h4[j]);
    vvf[tid]       = vvec[tid];
    vvf[128 + tid] = vvec[128 + tid];
    vvf[256 + tid] = vvec[256 + tid];
    vvf[384 + tid] = vvec[384 + tid];
  }
  __syncthreads();
  // dec_proj partials: unit=h8 (64), 2 threads per unit (k-halves of 256)
  {
    int ksel = tid >> 6, h8 = tid & 63;
    const short* wp = wdecT + (size_t)(ksel*256)*HH + h8*8;
    const float* hrow = hbf + ksel*256;
    float a[8] = {0.f,0.f,0.f,0.f,0.f,0.f,0.f,0.f};
    #pragma unroll 4
    for (int k = 0; k < 256; ++k) {
      bf16x8 w8 = *(const bf16x8*)(wp + (size_t)k*HH);
      float x = hrow[k];
      #pragma unroll
      for (int j = 0; j < 8; ++j) a[j] += x * bf2f(w8[j]);
    }
    float* d = dps[ksel] + h8*8;
    #pragma unroll
    for (int j = 0; j < 8; ++j) d[j] = a[j];
  }
  __syncthreads();
  {   // combine k-halves into dps[0][*]
    int h0_ = tid*4;
    f32x4 s0 = *(f32x4*)&dps[0][h0_];
    f32x4 s1 = *(f32x4*)&dps[1][h0_];
    *(f32x4*)&dps[0][h0_] = s0 + s1;
  }
  __syncthreads();
  // scores: unit=s (64), 2 lanes per unit (h-halves of 256)
  {
    int s = (tid >> 1) & 63, khalf = tid & 1;
    const short* ep = enc_proj + ((size_t)b*SS + s)*HH + khalf*256;
    const float* dpp = dps[0] + khalf*256;
    const float* vp  = vvf + khalf*256;
    float accv = 0.f;
    #pragma unroll 4
    for (int hc = 0; hc < 32; ++hc) {
      bf16x8 e8 = *(const bf16x8*)(ep + hc*8);
      f32x4 d0 = *(const f32x4*)(dpp + hc*8);
      f32x4 d1 = *(const f32x4*)(dpp + hc*8 + 4);
      f32x4 v0 = *(const f32x4*)(vp + hc*8);
      f32x4 v1 = *(const f32x4*)(vp + hc*8 + 4);
      #pragma unroll
      for (int j = 0; j < 4; ++j) accv += v0[j]*tanh_fast(d0[j] + bf2f(e8[j]));
      #pragma unroll
      for (int j = 0; j < 4; ++j) accv += v1[j]*tanh_fast(d1[j] + bf2f(e8[4+j]));
    }
    accv += __shfl_xor(accv, 1, 64);
    if (khalf == 0) sc[s] = accv;
  }
  __syncthreads();
  if (tid < 64) {   // masked softmax on wave0
    int s = tid;
    int valid = mask[b*SS + s];
    float x = valid ? sc[s] : -INFINITY;
    float mx = x;
    #pragma unroll
    for (int off = 32; off; off >>= 1) mx = fmaxf(mx, __shfl_xor(mx, off, 64));
    float e = valid ? __expf(x - mx) : 0.f;
    float sum = e;
    #pragma unroll
    for (int off = 32; off; off >>= 1) sum += __shfl_xor(sum, off, 64);
    wt[s] = e / sum;
  }
  __syncthreads();
  {   // context: d-slice of 8 per thread, serial over s
    int d0 = tid*8;
    const short* eob = enc_out + (size_t)b*SS*DENC + d0;
    float ca[8] = {0.f,0.f,0.f,0.f,0.f,0.f,0.f,0.f};
    #pragma unroll 4
    for (int s = 0; s < SS; ++s) {
      float w = wt[s];
      bf16x8 e8 = *(const bf16x8*)(eob + (size_t)s*DENC);
      #pragma unroll
      for (int j = 0; j < 8; ++j) ca[j] += w * bf2f(e8[j]);
    }
    bf16x8 cb8;
    #pragma unroll
    for (int j = 0; j < 8; ++j) cb8[j] = f2bf(ca[j]);
    *(bf16x8*)&xcat0[(size_t)b*XW0 + EE + d0] = cb8;
    *(bf16x8*)&predcat[(size_t)b*PW + HH + d0] = cb8;
  }
  {   // embeddings for this step: xcat0 emb + predcat emb
    int tok = (t == 0) ? 2 : targets[b*TT + t - 1];
    short ev0 = embb[tok*EE + tid];
    short ev1 = embb[tok*EE + 128 + tid];
    xcat0[(size_t)b*XW0 + tid] = ev0;
    xcat0[(size_t)b*XW0 + 128 + tid] = ev1;
    predcat[(size_t)b*PW + HH + DENC + tid] = ev0;
    predcat[(size_t)b*PW + HH + DENC + 128 + tid] = ev1;
  }
}

// gates GEMM (interleaved cols n=4*h+gate) + fused LSTM cell epilogue.
// 1-D grid: blocks [0,256) = gate tiles; blocks [256,256+nOut) = out-GEMM(t-1).
__global__ __launch_bounds__(256)
void gates_fused(const short* __restrict__ A, const short* __restrict__ W,
                 const float* __restrict__ bias, float* __restrict__ cb,
                 short* __restrict__ d1, short* __restrict__ d2, short* __restrict__ d3,
                 int K, int layer,
                 const short* __restrict__ predprev, const short* __restrict__ wout,
                 const float* __restrict__ b_out, float* __restrict__ out, int t)
{
  __shared__ __align__(16) char smem[36864];
  const int tid = threadIdx.x;
  if (blockIdx.x >= 256) {
    if (t >= 1) out_role(blockIdx.x - 256, tid, smem, predprev, wout, b_out, out, t);
    return;
  }
  short* As = (short*)smem;
  short* Bs = (short*)(smem + 18432);
  const int rowBase = (blockIdx.x >> 5)*64, colBase = (blockIdx.x & 31)*64;
  f32x4 acc[2][2];
  #pragma unroll
  for (int i = 0; i < 2; ++i)
    #pragma unroll
    for (int j = 0; j < 2; ++j) acc[i][j] = {0.f,0.f,0.f,0.f};
  GemmPipe<64,64>::run(As, Bs, A, W, K, K, 0, K >> 6, rowBase, colBase, tid, acc);
  const int lane = tid & 63, wave = tid >> 6, ml = lane & 15, kq = lane >> 4;
  const int wm = (wave >> 1)*32, wn = (wave & 1)*32;
  float* Ct = (float*)smem;                    // 64*68*4 = 17408 <= 18432
  float bj0 = bias[colBase + wn + ml];
  float bj1 = bias[colBase + wn + 16 + ml];
  #pragma unroll
  for (int ii = 0; ii < 2; ++ii)
    #pragma unroll
    for (int jj = 0; jj < 2; ++jj)
      #pragma unroll
      for (int r2 = 0; r2 < 4; ++r2)
        Ct[(wm + ii*16 + kq*4 + r2)*68 + wn + jj*16 + ml] = acc[ii][jj][r2] + (jj ? bj1 : bj0);
  __syncthreads();
  #pragma unroll
  for (int kk = 0; kk < 4; ++kk) {
    int cidx = tid + kk*256;
    int m = cidx >> 4, hl = cidx & 15;
    float4 gv = *(float4*)&Ct[m*68 + hl*4];    // i,f,g,o
    int b_ = rowBase + m, h_ = (colBase >> 2) + hl;
    float cp = cb[b_*HH + h_];
    float cn = sigf(gv.y)*cp + sigf(gv.x)*tanhf(gv.z);
    float hn = sigf(gv.w)*tanhf(cn);
    cb[b_*HH + h_] = cn;
    short hb16 = f2bf(hn);
    if (layer == 0) {
      d1[(size_t)b_*XW1 + h_] = hb16;
      d2[(size_t)b_*XW0 + h_] = hb16;
    } else {
      d1[(size_t)b_*XW1 + h_] = hb16;
      d2[(size_t)b_*PW  + h_] = hb16;
      d3[(size_t)b_*HH  + h_] = hb16;
    }
  }
}

// trailing out-GEMM for the final step
__global__ __launch_bounds__(256)
void out_fin(const short* __restrict__ predprev, const short* __restrict__ wout,
             const float* __restrict__ b_out, float* __restrict__ out)
{
  __shared__ __align__(16) char smem[36864];
  out_role(blockIdx.x, threadIdx.x, smem, predprev, wout, b_out, out, TT);
}

// enc_proj = enc_out @ W_enc.T (M=32768, N=512, K=1024), bf16 out. BM=64, BN=128.
__global__ __launch_bounds__(256)
void enc_gemm(short* __restrict__ C, const short* __restrict__ A, const short* __restrict__ Bt,
              int K, int ldc)
{
  __shared__ __align__(16) char smem[55296];
  short* As = (short*)smem;                    // 2*64*72*2  = 18432
  short* Bs = (short*)(smem + 18432);          // 2*128*72*2 = 36864
  const int tid = threadIdx.x;
  const int rowBase = blockIdx.y*64, colBase = blockIdx.x*128;
  f32x4 acc[2][4];
  #pragma unroll
  for (int i = 0; i < 2; ++i)
    #pragma unroll
    for (int j = 0; j < 4; ++j) acc[i][j] = {0.f,0.f,0.f,0.f};
  GemmPipe<64,128>::run(As, Bs, A, Bt, K, K, 0, K >> 6, rowBase, colBase, tid, acc);
  const int lane = tid & 63, wave = tid >> 6, ml = lane & 15, kq = lane >> 4;
  const int wm = (wave >> 1)*32, wn = (wave & 1)*64;
  #pragma unroll
  for (int ii = 0; ii < 2; ++ii)
    #pragma unroll
    for (int jj = 0; jj < 4; ++jj) {
      int n = colBase + wn + jj*16 + ml;
      #pragma unroll
      for (int r2 = 0; r2 < 4; ++r2) {
        int m = rowBase + wm + ii*16 + kq*4 + r2;
        C[(size_t)m*ldc + n] = f2bf(acc[ii][jj][r2]);
      }
    }
}

// interleaved (n = 4*h + gate) bf16 weight concat
__global__ __launch_bounds__(256)
void build_wcat_bf(short* __restrict__ wcat0, short* __restrict__ wcat1,
                   const float* __restrict__ wih0, const float* __restrict__ whh0,
                   const float* __restrict__ wih1, const float* __restrict__ whh1)
{
  int idx = blockIdx.x*256 + threadIdx.x;
  const int N0 = G4H*XW0;
  if (idx < N0) {
    int n = idx / XW0, k = idx % XW0;
    int row = (n & 3)*HH + (n >> 2);
    float v = (k < EE+DENC) ? wih0[(size_t)row*(EE+DENC) + k] : whh0[(size_t)row*HH + (k - (EE+DENC))];
    wcat0[idx] = f2bf(v);
  } else {
    int j = idx - N0;
    int n = j / XW1, k = j % XW1;
    int row = (n & 3)*HH + (n >> 2);
    float v = (k < HH) ? wih1[(size_t)row*HH + k] : whh1[(size_t)row*HH + (k - HH)];
    wcat1[j] = f2bf(v);
  }
}

__global__ __launch_bounds__(256)
void cvt_encout(short* __restrict__ dst, const float* __restrict__ src)
{
  size_t i8 = ((size_t)blockIdx.x*256 + threadIdx.x)*8;
  float4 a = *(const float4*)&src[i8];
  float4 b = *(const float4*)&src[i8+4];
  bf16x8 o;
  o[0]=f2bf(a.x); o[1]=f2bf(a.y); o[2]=f2bf(a.z); o[3]=f2bf(a.w);
  o[4]=f2bf(b.x); o[5]=f2bf(b.y); o[6]=f2bf(b.z); o[7]=f2bf(b.w);
  *(bf16x8*)&dst[i8] = o;
}

__global__ __launch_bounds__(256)
void prep_misc(float* __restrict__ cbuf, short* __restrict__ xcat0a, short* __restrict__ xcat1a,
               short* __restrict__ hb, short* __restrict__ wdecT, short* __restrict__ wenc,
               short* __restrict__ wout, short* __restrict__ embb,
               float* __restrict__ bias0i, float* __restrict__ bias1i,
               const float* __restrict__ c0, const float* __restrict__ h0,
               const float* __restrict__ W_dec, const float* __restrict__ W_enc,
               const float* __restrict__ W_out, const float* __restrict__ emb,
               const float* __restrict__ b_ih0, const float* __restrict__ b_hh0,
               const float* __restrict__ b_ih1, const float* __restrict__ b_hh1)
{
  int idx = blockIdx.x*256 + threadIdx.x;
  if (idx < 524288) { cbuf[idx] = c0[idx]; return; }
  idx -= 524288;
  if (idx < 262144) {
    int b = idx >> 9, h = idx & 511;
    xcat0a[(size_t)b*XW0 + EE + DENC + h] = f2bf(h0[idx]);
    return;
  }
  idx -= 262144;
  if (idx < 262144) {
    int b = idx >> 9, h = idx & 511;
    short v = f2bf(h0[BH + idx]);
    xcat1a[(size_t)b*XW1 + HH + h] = v;
    hb[idx] = v;
    return;
  }
  idx -= 262144;
  if (idx < 262144) {                           // wdecT[k][n] = W_dec[n][k]
    int k = idx >> 9, n = idx & 511;
    wdecT[idx] = f2bf(W_dec[(size_t)n*HH + k]);
    return;
  }
  idx -= 262144;
  if (idx < 524288) { wenc[idx] = f2bf(W_enc[idx]); return; }
  idx -= 524288;
  if (idx < 229376) { wout[idx] = f2bf(W_out[idx]); return; }
  idx -= 229376;
  if (idx < 32768)  { embb[idx] = f2bf(emb[idx]); return; }
  idx -= 32768;
  if (idx < 2048) {
    int row = (idx & 3)*HH + (idx >> 2);
    bias0i[idx] = b_ih0[row] + b_hh0[row];
    return;
  }
  idx -= 2048;
  {
    int row = (idx & 3)*HH + (idx >> 2);
    bias1i[idx] = b_ih1[row] + b_hh1[row];
  }
}

extern "C" void kernel_launch(void* const* d_in, const int* in_sizes, int n_in,
                              void* d_out, int out_size, void* d_ws, size_t ws_size,
                              hipStream_t stream) {
  const float* enc_out = (const float*)d_in[0];
  const float* h0      = (const float*)d_in[1];
  const float* c0      = (const float*)d_in[2];
  const int*   targets = (const int*)d_in[3];
  const int*   mask    = (const int*)d_in[4];
  const float* emb     = (const float*)d_in[5];
  const float* W_enc   = (const float*)d_in[6];
  const float* W_dec   = (const float*)d_in[7];
  const float* v       = (const float*)d_in[8];
  const float* b_ih0   = (const float*)d_in[11];
  const float* b_hh0   = (const float*)d_in[12];
  const float* b_ih1   = (const float*)d_in[15];
  const float* b_hh1   = (const float*)d_in[16];
  const float* b_out   = (const float*)d_in[18];
  float* out = (float*)d_out;

  char* ws = (char*)d_ws;
  size_t o = 0;
  short* enc_out_bf = (short*)(ws + o); o += (size_t)BB*SS*DENC*2;
  short* enc_proj_bf= (short*)(ws + o); o += (size_t)BB*SS*HH*2;
  short* wcat0i     = (short*)(ws + o); o += (size_t)G4H*XW0*2;
  short* wcat1i     = (short*)(ws + o); o += (size_t)G4H*XW1*2;
  short* wdecT      = (short*)(ws + o); o += (size_t)HH*HH*2;
  short* wenc_bf    = (short*)(ws + o); o += (size_t)HH*DENC*2;
  short* wout_bf    = (short*)(ws + o); o += (size_t)VV*PW*2;
  short* emb_bf     = (short*)(ws + o); o += (size_t)VV*EE*2;
  short* xcat0a     = (short*)(ws + o); o += (size_t)BB*XW0*2;
  short* xcat0b     = (short*)(ws + o); o += (size_t)BB*XW0*2;
  short* xcat1a     = (short*)(ws + o); o += (size_t)BB*XW1*2;
  short* xcat1b     = (short*)(ws + o); o += (size_t)BB*XW1*2;
  short* predcata   = (short*)(ws + o); o += (size_t)BB*PW*2;
  short* predcatb   = (short*)(ws + o); o += (size_t)BB*PW*2;
  short* hb         = (short*)(ws + o); o += (size_t)BH*2;
  float* cbuf       = (float*)(ws + o); o += (size_t)2*BH*4;
  float* bias0i     = (float*)(ws + o); o += (size_t)G4H*4;
  float* bias1i     = (float*)(ws + o); o += (size_t)G4H*4;
  (void)ws_size; (void)in_sizes; (void)n_in; (void)out_size;

  cvt_encout<<<16384, 256, 0, stream>>>(enc_out_bf, enc_out);
  build_wcat_bf<<<22528, 256, 0, stream>>>(wcat0i, wcat1i,
      (const float*)d_in[9], (const float*)d_in[10], (const float*)d_in[13], (const float*)d_in[14]);
  prep_misc<<<8208, 256, 0, stream>>>(cbuf, xcat0a, xcat1a, hb, wdecT, wenc_bf, wout_bf, emb_bf,
      bias0i, bias1i, c0, h0, W_dec, W_enc, (const float*)d_in[17], emb,
      b_ih0, b_hh0, b_ih1, b_hh1);
  enc_gemm<<<dim3(HH/128, (BB*SS)/64), 256, 0, stream>>>(
      enc_proj_bf, enc_out_bf, wenc_bf, DENC, HH);

  short* xc0[2] = {xcat0a, xcat0b};
  short* xc1[2] = {xcat1a, xcat1b};
  short* pc[2]  = {predcata, predcatb};
  for (int t = 0; t < TT; ++t) {
    attn_row<<<512, 128, 0, stream>>>(enc_proj_bf, enc_out_bf, v, mask, targets, emb_bf,
        hb, wdecT, xc0[t&1], pc[t&1], t);
    // gates0 (256 tiles) + out-GEMM for step t-1 (16 tiles) in one launch
    gates_fused<<<272, 256, 0, stream>>>(
        xc0[t&1], wcat0i, bias0i, cbuf, xc1[t&1], xc0[(t+1)&1] + EE + DENC, (short*)nullptr,
        XW0, 0, pc[(t+1)&1], wout_bf, b_out, out, t);
    gates_fused<<<256, 256, 0, stream>>>(
        xc1[t&1], wcat1i, bias1i, cbuf + BH, xc1[(t+1)&1] + HH, pc[t&1], hb,
        XW1, 1, (const short*)nullptr, (const short*)nullptr, (const float*)nullptr,
        (float*)nullptr, 0);
  }
  out_fin<<<16, 256, 0, stream>>>(pc[1], wout_bf, b_out, out);
}

// Round 5
// 2796.631 us; speedup vs baseline: 8.2137x; 1.1112x over previous
//
#include <hip/hip_runtime.h>
#include <math.h>

#define BB 512
#define SS 64
#define TT 32
#define VV 128
#define EE 256
#define HH 512
#define DENC 1024
#define BH (BB*HH)
#define XW0 1792   // E + DENC + H
#define XW1 1024   // H + H
#define PW  1792   // H + DENC + E
#define G4H 2048   // 4*H

typedef __attribute__((ext_vector_type(8))) short bf16x8;
typedef __attribute__((ext_vector_type(4))) short bf16x4;
typedef __attribute__((ext_vector_type(4))) float f32x4;

__device__ __forceinline__ float sigf(float x){ return 1.f/(1.f+expf(-x)); }
__device__ __forceinline__ float bf2f(short s){
  return __uint_as_float(((unsigned)(unsigned short)s) << 16);
}
__device__ __forceinline__ short f2bf(float f){
  unsigned u = __float_as_uint(f);
  return (short)((u + 0x7FFF + ((u>>16)&1)) >> 16);   // RNE
}
__device__ __forceinline__ float tanh_fast(float x){
  x = fminf(fmaxf(x, -15.f), 15.f);
  float e = __expf(2.f*x);
  return (e - 1.f) / (e + 1.f);
}

__device__ __forceinline__ void zacc(f32x4 a[2][2]){
  #pragma unroll
  for (int i = 0; i < 2; ++i)
    #pragma unroll
    for (int j = 0; j < 2; ++j) a[i][j] = {0.f,0.f,0.f,0.f};
}

// Double-buffered pipelined bf16 MFMA GEMM core. BK=64, one barrier per iter.
// LDS row stride 72 shorts (2-way bank aliasing only).
// Wave w computes tile (BM/2)x(BN/2) at wm=(w>>1)*(BM/2), wn=(w&1)*(BN/2).
template<int BM, int BN>
struct GemmPipe {
  static constexpr int LA = 72;
  static __device__ __forceinline__ void run(short* Asb, short* Bsb,
      const short* __restrict__ A, const short* __restrict__ Bt,
      int lda, int ldb, int kBase, int nIter,
      int rowBase, int colBase, int tid, f32x4 acc[BM/32][BN/32])
  {
    constexpr int FI = BM/32, FJ = BN/32, ACH = BM/32, BCH = BN/32;
    const int lane = tid & 63, wave = tid >> 6;
    const int ml = lane & 15, kq = lane >> 4;
    const int wm = (wave >> 1)*(BM/2), wn = (wave & 1)*(BN/2);
    const int arow = (tid*ACH) >> 3, acol = ((tid*ACH) & 7)*8;
    const int brow = (tid*BCH) >> 3, bcol = ((tid*BCH) & 7)*8;
    const short* Ap = A + (size_t)(rowBase+arow)*lda + kBase + acol;
    const short* Bp = Bt + (size_t)(colBase+brow)*ldb + kBase + bcol;
    bf16x8 ar[ACH], br[BCH];
    #pragma unroll
    for (int c = 0; c < ACH; ++c) ar[c] = *(const bf16x8*)(Ap + c*8);
    #pragma unroll
    for (int c = 0; c < BCH; ++c) br[c] = *(const bf16x8*)(Bp + c*8);
    for (int i = 0; i < nIter; ++i) {
      short* Ab = Asb + (i&1)*(BM*LA);
      short* Bb = Bsb + (i&1)*(BN*LA);
      #pragma unroll
      for (int c = 0; c < ACH; ++c) *(bf16x8*)&Ab[arow*LA + acol + c*8] = ar[c];
      #pragma unroll
      for (int c = 0; c < BCH; ++c) *(bf16x8*)&Bb[brow*LA + bcol + c*8] = br[c];
      __syncthreads();
      if (i+1 < nIter) {
        const short* An = Ap + (size_t)(i+1)*64;
        const short* Bn = Bp + (size_t)(i+1)*64;
        #pragma unroll
        for (int c = 0; c < ACH; ++c) ar[c] = *(const bf16x8*)(An + c*8);
        #pragma unroll
        for (int c = 0; c < BCH; ++c) br[c] = *(const bf16x8*)(Bn + c*8);
      }
      #pragma unroll
      for (int kh = 0; kh < 2; ++kh) {
        bf16x8 af[FI], bfv[FJ];
        #pragma unroll
        for (int ii = 0; ii < FI; ++ii)
          af[ii] = *(const bf16x8*)&Ab[(wm + ii*16 + ml)*LA + kh*32 + kq*8];
        #pragma unroll
        for (int jj = 0; jj < FJ; ++jj)
          bfv[jj] = *(const bf16x8*)&Bb[(wn + jj*16 + ml)*LA + kh*32 + kq*8];
        #pragma unroll
        for (int ii = 0; ii < FI; ++ii)
          #pragma unroll
          for (int jj = 0; jj < FJ; ++jj)
            acc[ii][jj] = __builtin_amdgcn_mfma_f32_16x16x32_bf16(af[ii], bfv[jj], acc[ii][jj], 0,0,0);
      }
    }
    __syncthreads();
  }
};

// ---------------- shared device roles ----------------

// attention for b = 2*aid, 2*aid+1 (256 threads). Writes ctx into xcat0/predcat
// and emb into predcat. Does NOT write xcat0 emb (prewritten one step ahead).
__device__ __forceinline__ void attn_role(int aid, int tid, char* smem, int t,
    const short* __restrict__ enc_proj, const short* __restrict__ enc_out,
    const float* __restrict__ vvec, const int* __restrict__ mask,
    const int* __restrict__ targets, const short* __restrict__ embb,
    const short* __restrict__ hb, const short* __restrict__ wdecT,
    short* __restrict__ xcat0, short* __restrict__ predcat)
{
  const int b0 = aid*2;
  float* hbf = (float*)smem;                  // [2][512]
  float* dps = (float*)(smem + 4096);         // [ksel][b][512]
  float* vvf = (float*)(smem + 12288);        // [512]
  float* sc  = (float*)(smem + 14336);        // [2][64]
  float* wt  = (float*)(smem + 14848);        // [2][64]
  {
    bf16x4 h4 = *(const bf16x4*)&hb[(size_t)b0*HH + tid*4];
    #pragma unroll
    for (int j = 0; j < 4; ++j) hbf[tid*4 + j] = bf2f(h4[j]);
    vvf[tid] = vvec[tid];
    vvf[256 + tid] = vvec[256 + tid];
  }
  __syncthreads();
  // dec_proj partials: unit=(b,h8), 2 threads per unit (k-halves of 256)
  {
    int unit = tid & 127, ksel = tid >> 7;
    int bb = unit >> 6, h8 = unit & 63;
    const short* wp = wdecT + (size_t)(ksel*256)*HH + h8*8;
    const float* hrow = hbf + bb*HH + ksel*256;
    float a[8] = {0.f,0.f,0.f,0.f,0.f,0.f,0.f,0.f};
    for (int k = 0; k < 256; ++k) {
      bf16x8 w8 = *(const bf16x8*)(wp + (size_t)k*HH);
      float x = hrow[k];
      #pragma unroll
      for (int j = 0; j < 8; ++j) a[j] += x * bf2f(w8[j]);
    }
    float* d = dps + (ksel*2 + bb)*HH + h8*8;
    #pragma unroll
    for (int j = 0; j < 8; ++j) d[j] = a[j];
  }
  __syncthreads();
  {   // combine k-halves
    int bb = tid >> 7, h0_ = (tid & 127)*4;
    f32x4 s0 = *(f32x4*)&dps[bb*HH + h0_];
    f32x4 s1 = *(f32x4*)&dps[(2 + bb)*HH + h0_];
    *(f32x4*)&dps[bb*HH + h0_] = s0 + s1;
  }
  __syncthreads();
  // scores: unit=(b,s), 2 lanes per unit (h-halves of 256)
  {
    int u = tid >> 1, khalf = tid & 1;
    int bb = u >> 6, s = u & 63;
    const short* ep = enc_proj + ((size_t)(b0+bb)*SS + s)*HH + khalf*256;
    const float* dpp = dps + bb*HH + khalf*256;
    const float* vp  = vvf + khalf*256;
    float accv = 0.f;
    for (int hc = 0; hc < 32; ++hc) {
      bf16x8 e8 = *(const bf16x8*)(ep + hc*8);
      f32x4 d0 = *(const f32x4*)(dpp + hc*8);
      f32x4 d1 = *(const f32x4*)(dpp + hc*8 + 4);
      f32x4 v0 = *(const f32x4*)(vp + hc*8);
      f32x4 v1 = *(const f32x4*)(vp + hc*8 + 4);
      #pragma unroll
      for (int j = 0; j < 4; ++j) accv += v0[j]*tanh_fast(d0[j] + bf2f(e8[j]));
      #pragma unroll
      for (int j = 0; j < 4; ++j) accv += v1[j]*tanh_fast(d1[j] + bf2f(e8[4+j]));
    }
    accv += __shfl_xor(accv, 1, 64);
    if (khalf == 0) sc[bb*64 + s] = accv;
  }
  __syncthreads();
  if (tid < 128) {   // masked softmax: wave0 -> b0, wave1 -> b1
    int bb = tid >> 6, s = tid & 63;
    int valid = mask[(b0+bb)*SS + s];
    float x = valid ? sc[bb*64 + s] : -INFINITY;
    float mx = x;
    #pragma unroll
    for (int off = 32; off; off >>= 1) mx = fmaxf(mx, __shfl_xor(mx, off, 64));
    float e = valid ? __expf(x - mx) : 0.f;
    float sum = e;
    #pragma unroll
    for (int off = 32; off; off >>= 1) sum += __shfl_xor(sum, off, 64);
    wt[bb*64 + s] = e / sum;
  }
  __syncthreads();
  {   // context
    int bb = tid >> 7, d0 = (tid & 127)*8;
    const short* eob = enc_out + (size_t)(b0+bb)*SS*DENC + d0;
    float ca[8] = {0.f,0.f,0.f,0.f,0.f,0.f,0.f,0.f};
    for (int s = 0; s < SS; ++s) {
      float w = wt[bb*64 + s];
      bf16x8 e8 = *(const bf16x8*)(eob + (size_t)s*DENC);
      #pragma unroll
      for (int j = 0; j < 8; ++j) ca[j] += w * bf2f(e8[j]);
    }
    bf16x8 cb8;
    #pragma unroll
    for (int j = 0; j < 8; ++j) cb8[j] = f2bf(ca[j]);
    int b_ = b0 + bb;
    *(bf16x8*)&xcat0[(size_t)b_*XW0 + EE + d0] = cb8;
    *(bf16x8*)&predcat[(size_t)b_*PW + HH + d0] = cb8;
  }
  #pragma unroll
  for (int bb = 0; bb < 2; ++bb) {   // predcat emb (xcat0 emb prewritten)
    int b_ = b0 + bb;
    int tok = (t == 0) ? 2 : targets[b_*TT + t - 1];
    predcat[(size_t)b_*PW + HH + DENC + tid] = embb[tok*EE + tid];
  }
}

// out GEMM for one 64x64 tile: out[:, t-1, :] = predprev @ wout.T + b_out
__device__ __forceinline__ void out_role(int idx, int tid, char* smem,
    const short* __restrict__ predprev, const short* __restrict__ wout,
    const float* __restrict__ b_out, float* __restrict__ out, int t)
{
  short* As = (short*)smem;
  short* Bs = (short*)(smem + 18432);
  const int rowBase = (idx >> 1)*64, colBase = (idx & 1)*64;
  f32x4 acc[2][2];
  zacc(acc);
  GemmPipe<64,64>::run(As, Bs, predprev, wout, PW, PW, 0, PW/64, rowBase, colBase, tid, acc);
  const int lane = tid & 63, wave = tid >> 6, ml = lane & 15, kq = lane >> 4;
  const int wm = (wave >> 1)*32, wn = (wave & 1)*32;
  #pragma unroll
  for (int ii = 0; ii < 2; ++ii)
    #pragma unroll
    for (int jj = 0; jj < 2; ++jj) {
      int n = colBase + wn + jj*16 + ml;
      float bv = b_out[n];
      #pragma unroll
      for (int r2 = 0; r2 < 4; ++r2) {
        int m = rowBase + wm + ii*16 + kq*4 + r2;
        out[(size_t)m*(TT*VV) + (size_t)(t-1)*VV + n] = acc[ii][jj][r2] + bv;
      }
    }
}

// store f32 partial accumulator tile to P[512][G4H]
__device__ __forceinline__ void pstore(int tid, int rowBase, int colBase,
    float* __restrict__ P, f32x4 acc[2][2])
{
  const int lane = tid & 63, wave = tid >> 6, ml = lane & 15, kq = lane >> 4;
  const int wm = (wave >> 1)*32, wn = (wave & 1)*32;
  #pragma unroll
  for (int ii = 0; ii < 2; ++ii)
    #pragma unroll
    for (int jj = 0; jj < 2; ++jj)
      #pragma unroll
      for (int r2 = 0; r2 < 4; ++r2)
        P[(size_t)(rowBase + wm + ii*16 + kq*4 + r2)*G4H + colBase + wn + jj*16 + ml] = acc[ii][jj][r2];
}

// LSTM cell epilogue (gate cols n = 4*h + gate, interleaved)
__device__ __forceinline__ void gates_epi(int tid, int rowBase, int colBase,
    char* smem, f32x4 acc[2][2], const float* __restrict__ bias,
    float* __restrict__ cb,
    short* __restrict__ d1, int ld1, short* __restrict__ d2, int ld2,
    short* __restrict__ d3)
{
  const int lane = tid & 63, wave = tid >> 6, ml = lane & 15, kq = lane >> 4;
  const int wm = (wave >> 1)*32, wn = (wave & 1)*32;
  float* Ct = (float*)smem;                    // 64*68*4 = 17408 <= 18432
  float bj0 = bias[colBase + wn + ml];
  float bj1 = bias[colBase + wn + 16 + ml];
  #pragma unroll
  for (int ii = 0; ii < 2; ++ii)
    #pragma unroll
    for (int jj = 0; jj < 2; ++jj)
      #pragma unroll
      for (int r2 = 0; r2 < 4; ++r2)
        Ct[(wm + ii*16 + kq*4 + r2)*68 + wn + jj*16 + ml] = acc[ii][jj][r2] + (jj ? bj1 : bj0);
  __syncthreads();
  #pragma unroll
  for (int kk = 0; kk < 4; ++kk) {
    int cidx = tid + kk*256;
    int m = cidx >> 4, hl = cidx & 15;
    float4 gv = *(float4*)&Ct[m*68 + hl*4];    // i,f,g,o
    int b_ = rowBase + m, h_ = (colBase >> 2) + hl;
    float cp = cb[b_*HH + h_];
    float cn = sigf(gv.y)*cp + sigf(gv.x)*tanhf(gv.z);
    float hn = sigf(gv.w)*tanhf(cn);
    cb[b_*HH + h_] = cn;
    short hb16 = f2bf(hn);
    d1[(size_t)b_*ld1 + h_] = hb16;
    d2[(size_t)b_*ld2 + h_] = hb16;
    if (d3) d3[(size_t)b_*HH + h_] = hb16;
  }
}

// write emb(token for step t+1) into next xcat0 buffer: 64 b-rows from rowBase
__device__ __forceinline__ void emb_prewrite(int rowBase, int tid,
    short* __restrict__ xc0n, const int* __restrict__ targets,
    const short* __restrict__ embb, int t)
{
  int b_ = rowBase + (tid >> 2);
  int tok = targets[b_*TT + t];
  const short* src = embb + tok*EE + (tid & 3)*64;
  short* dst = xc0n + (size_t)b_*XW0 + (tid & 3)*64;
  #pragma unroll
  for (int j = 0; j < 8; ++j)
    *(bf16x8*)(dst + j*8) = *(const bf16x8*)(src + j*8);
}

// ---------------- per-step kernels ----------------

// Launch A: blocks [0,256) attn (2 rows each); [256,512) partial-gates0
// over K = emb[0,256) U h0prev[1280,1792) -> P0; [512,528) out-GEMM(t-1).
// No intra-launch dependencies: partial reads xcat0 cols disjoint from the
// ctx cols attn writes (byte ranges split at 512/2560, cache-line aligned).
__global__ __launch_bounds__(256)
void attn_pg0(const short* __restrict__ enc_proj, const short* __restrict__ enc_out,
              const float* __restrict__ vvec, const int* __restrict__ mask,
              const int* __restrict__ targets, const short* __restrict__ embb,
              const short* __restrict__ hb, const short* __restrict__ wdecT,
              short* __restrict__ xcat0, short* __restrict__ predcat,
              const short* __restrict__ wcat0, float* __restrict__ P0,
              const short* __restrict__ predprev, const short* __restrict__ wout,
              const float* __restrict__ b_out, float* __restrict__ out, int t)
{
  __shared__ __align__(16) char smem[36864];
  const int tid = threadIdx.x, bid = blockIdx.x;
  if (bid < 256) {
    attn_role(bid, tid, smem, t, enc_proj, enc_out, vvec, mask, targets,
              embb, hb, wdecT, xcat0, predcat);
  } else if (bid < 512) {
    short* As = (short*)smem;
    short* Bs = (short*)(smem + 18432);
    int idx = bid - 256;
    int rowBase = (idx >> 5)*64, colBase = (idx & 31)*64;
    f32x4 acc[2][2];
    zacc(acc);
    GemmPipe<64,64>::run(As, Bs, xcat0, wcat0, XW0, XW0, 0,    4, rowBase, colBase, tid, acc);
    GemmPipe<64,64>::run(As, Bs, xcat0, wcat0, XW0, XW0, 1280, 8, rowBase, colBase, tid, acc);
    pstore(tid, rowBase, colBase, P0, acc);
  } else {
    if (t >= 1) out_role(bid - 512, tid, smem, predprev, wout, b_out, out, t);
  }
}

// Launch B: blocks [0,256) gates0 finish (ctx K, 16 iters, acc seeded from P0)
// + LSTM0 epilogue; blocks [256,264) emb prewrite for step t+1.
__global__ __launch_bounds__(256)
void gates0_fin(const short* __restrict__ A, const short* __restrict__ W,
                const float* __restrict__ bias, const float* __restrict__ P0,
                float* __restrict__ cb,
                short* __restrict__ d1, short* __restrict__ d2,
                short* __restrict__ xc0n, const int* __restrict__ targets,
                const short* __restrict__ embb, int t)
{
  __shared__ __align__(16) char smem[36864];
  const int tid = threadIdx.x, bid = blockIdx.x;
  if (bid >= 256) {
    if (t + 1 < TT) emb_prewrite((bid - 256)*64, tid, xc0n, targets, embb, t);
    return;
  }
  short* As = (short*)smem;
  short* Bs = (short*)(smem + 18432);
  const int rowBase = (bid >> 5)*64, colBase = (bid & 31)*64;
  const int lane = tid & 63, wave = tid >> 6, ml = lane & 15, kq = lane >> 4;
  const int wm = (wave >> 1)*32, wn = (wave & 1)*32;
  f32x4 acc[2][2];
  const float* Pp = P0 + (size_t)rowBase*G4H + colBase;
  #pragma unroll
  for (int ii = 0; ii < 2; ++ii)
    #pragma unroll
    for (int jj = 0; jj < 2; ++jj)
      #pragma unroll
      for (int r2 = 0; r2 < 4; ++r2)
        acc[ii][jj][r2] = Pp[(wm + ii*16 + kq*4 + r2)*G4H + wn + jj*16 + ml];
  GemmPipe<64,64>::run(As, Bs, A, W, XW0, XW0, 256, 16, rowBase, colBase, tid, acc);
  gates_epi(tid, rowBase, colBase, smem, acc, bias, cb, d1, XW1, d2, XW0, (short*)nullptr);
}

// Launch C: gates1 full (K=1024, 16 iters) + LSTM1 epilogue.
__global__ __launch_bounds__(256)
void gates1_full(const short* __restrict__ A, const short* __restrict__ W,
                 const float* __restrict__ bias, float* __restrict__ cb,
                 short* __restrict__ d1, short* __restrict__ d2, short* __restrict__ d3)
{
  __shared__ __align__(16) char smem[36864];
  const int tid = threadIdx.x, bid = blockIdx.x;
  short* As = (short*)smem;
  short* Bs = (short*)(smem + 18432);
  const int rowBase = (bid >> 5)*64, colBase = (bid & 31)*64;
  f32x4 acc[2][2];
  zacc(acc);
  GemmPipe<64,64>::run(As, Bs, A, W, XW1, XW1, 0, 16, rowBase, colBase, tid, acc);
  gates_epi(tid, rowBase, colBase, smem, acc, bias, cb, d1, XW1, d2, PW, d3);
}

// trailing out-GEMM for the final step
__global__ __launch_bounds__(256)
void out_fin(const short* __restrict__ predprev, const short* __restrict__ wout,
             const float* __restrict__ b_out, float* __restrict__ out)
{
  __shared__ __align__(16) char smem[36864];
  out_role(blockIdx.x, threadIdx.x, smem, predprev, wout, b_out, out, TT);
}

// enc_proj = enc_out @ W_enc.T (M=32768, N=512, K=1024), bf16 out. BM=64, BN=128.
__global__ __launch_bounds__(256)
void enc_gemm(short* __restrict__ C, const short* __restrict__ A, const short* __restrict__ Bt,
              int K, int ldc)
{
  __shared__ __align__(16) char smem[55296];
  short* As = (short*)smem;                    // 2*64*72*2  = 18432
  short* Bs = (short*)(smem + 18432);          // 2*128*72*2 = 36864
  const int tid = threadIdx.x;
  const int rowBase = blockIdx.y*64, colBase = blockIdx.x*128;
  f32x4 acc[2][4];
  #pragma unroll
  for (int i = 0; i < 2; ++i)
    #pragma unroll
    for (int j = 0; j < 4; ++j) acc[i][j] = {0.f,0.f,0.f,0.f};
  GemmPipe<64,128>::run(As, Bs, A, Bt, K, K, 0, K >> 6, rowBase, colBase, tid, acc);
  const int lane = tid & 63, wave = tid >> 6, ml = lane & 15, kq = lane >> 4;
  const int wm = (wave >> 1)*32, wn = (wave & 1)*64;
  #pragma unroll
  for (int ii = 0; ii < 2; ++ii)
    #pragma unroll
    for (int jj = 0; jj < 4; ++jj) {
      int n = colBase + wn + jj*16 + ml;
      #pragma unroll
      for (int r2 = 0; r2 < 4; ++r2) {
        int m = rowBase + wm + ii*16 + kq*4 + r2;
        C[(size_t)m*ldc + n] = f2bf(acc[ii][jj][r2]);
      }
    }
}

// interleaved (n = 4*h + gate) bf16 weight concat
__global__ __launch_bounds__(256)
void build_wcat_bf(short* __restrict__ wcat0, short* __restrict__ wcat1,
                   const float* __restrict__ wih0, const float* __restrict__ whh0,
                   const float* __restrict__ wih1, const float* __restrict__ whh1)
{
  int idx = blockIdx.x*256 + threadIdx.x;
  const int N0 = G4H*XW0;
  if (idx < N0) {
    int n = idx / XW0, k = idx % XW0;
    int row = (n & 3)*HH + (n >> 2);
    float v = (k < EE+DENC) ? wih0[(size_t)row*(EE+DENC) + k] : whh0[(size_t)row*HH + (k - (EE+DENC))];
    wcat0[idx] = f2bf(v);
  } else {
    int j = idx - N0;
    int n = j / XW1, k = j % XW1;
    int row = (n & 3)*HH + (n >> 2);
    float v = (k < HH) ? wih1[(size_t)row*HH + k] : whh1[(size_t)row*HH + (k - HH)];
    wcat1[j] = f2bf(v);
  }
}

__global__ __launch_bounds__(256)
void cvt_encout(short* __restrict__ dst, const float* __restrict__ src)
{
  size_t i8 = ((size_t)blockIdx.x*256 + threadIdx.x)*8;
  float4 a = *(const float4*)&src[i8];
  float4 b = *(const float4*)&src[i8+4];
  bf16x8 o;
  o[0]=f2bf(a.x); o[1]=f2bf(a.y); o[2]=f2bf(a.z); o[3]=f2bf(a.w);
  o[4]=f2bf(b.x); o[5]=f2bf(b.y); o[6]=f2bf(b.z); o[7]=f2bf(b.w);
  *(bf16x8*)&dst[i8] = o;
}

__global__ __launch_bounds__(256)
void prep_misc(float* __restrict__ cbuf, short* __restrict__ xcat0a, short* __restrict__ xcat1a,
               short* __restrict__ hb, short* __restrict__ wdecT, short* __restrict__ wenc,
               short* __restrict__ wout, short* __restrict__ embb,
               float* __restrict__ bias0i, float* __restrict__ bias1i,
               const float* __restrict__ c0, const float* __restrict__ h0,
               const float* __restrict__ W_dec, const float* __restrict__ W_enc,
               const float* __restrict__ W_out, const float* __restrict__ emb,
               const float* __restrict__ b_ih0, const float* __restrict__ b_hh0,
               const float* __restrict__ b_ih1, const float* __restrict__ b_hh1)
{
  int idx = blockIdx.x*256 + threadIdx.x;
  if (idx < 524288) { cbuf[idx] = c0[idx]; return; }
  idx -= 524288;
  if (idx < 262144) {
    int b = idx >> 9, h = idx & 511;
    xcat0a[(size_t)b*XW0 + EE + DENC + h] = f2bf(h0[idx]);
    return;
  }
  idx -= 262144;
  if (idx < 262144) {
    int b = idx >> 9, h = idx & 511;
    short v = f2bf(h0[BH + idx]);
    xcat1a[(size_t)b*XW1 + HH + h] = v;
    hb[idx] = v;
    return;
  }
  idx -= 262144;
  if (idx < 262144) {                           // wdecT[k][n] = W_dec[n][k]
    int k = idx >> 9, n = idx & 511;
    wdecT[idx] = f2bf(W_dec[(size_t)n*HH + k]);
    return;
  }
  idx -= 262144;
  if (idx < 524288) { wenc[idx] = f2bf(W_enc[idx]); return; }
  idx -= 524288;
  if (idx < 229376) { wout[idx] = f2bf(W_out[idx]); return; }
  idx -= 229376;
  if (idx < 32768)  { embb[idx] = f2bf(emb[idx]); return; }
  idx -= 32768;
  if (idx < 2048) {
    int row = (idx & 3)*HH + (idx >> 2);
    bias0i[idx] = b_ih0[row] + b_hh0[row];
    return;
  }
  idx -= 2048;
  if (idx < 2048) {
    int row = (idx & 3)*HH + (idx >> 2);
    bias1i[idx] = b_ih1[row] + b_hh1[row];
    return;
  }
  idx -= 2048;
  {                                             // emb(t=0) = emb[EOS=2] into xcat0a
    int b = idx >> 8, e = idx & 255;
    xcat0a[(size_t)b*XW0 + e] = f2bf(emb[2*EE + e]);
  }
}

extern "C" void kernel_launch(void* const* d_in, const int* in_sizes, int n_in,
                              void* d_out, int out_size, void* d_ws, size_t ws_size,
                              hipStream_t stream) {
  const float* enc_out = (const float*)d_in[0];
  const float* h0      = (const float*)d_in[1];
  const float* c0      = (const float*)d_in[2];
  const int*   targets = (const int*)d_in[3];
  const int*   mask    = (const int*)d_in[4];
  const float* emb     = (const float*)d_in[5];
  const float* W_enc   = (const float*)d_in[6];
  const float* W_dec   = (const float*)d_in[7];
  const float* v       = (const float*)d_in[8];
  const float* b_ih0   = (const float*)d_in[11];
  const float* b_hh0   = (const float*)d_in[12];
  const float* b_ih1   = (const float*)d_in[15];
  const float* b_hh1   = (const float*)d_in[16];
  const float* b_out   = (const float*)d_in[18];
  float* out = (float*)d_out;

  char* ws = (char*)d_ws;
  size_t o = 0;
  short* enc_out_bf = (short*)(ws + o); o += (size_t)BB*SS*DENC*2;
  short* enc_proj_bf= (short*)(ws + o); o += (size_t)BB*SS*HH*2;
  short* wcat0i     = (short*)(ws + o); o += (size_t)G4H*XW0*2;
  short* wcat1i     = (short*)(ws + o); o += (size_t)G4H*XW1*2;
  short* wdecT      = (short*)(ws + o); o += (size_t)HH*HH*2;
  short* wenc_bf    = (short*)(ws + o); o += (size_t)HH*DENC*2;
  short* wout_bf    = (short*)(ws + o); o += (size_t)VV*PW*2;
  short* emb_bf     = (short*)(ws + o); o += (size_t)VV*EE*2;
  short* xcat0a     = (short*)(ws + o); o += (size_t)BB*XW0*2;
  short* xcat0b     = (short*)(ws + o); o += (size_t)BB*XW0*2;
  short* xcat1a     = (short*)(ws + o); o += (size_t)BB*XW1*2;
  short* xcat1b     = (short*)(ws + o); o += (size_t)BB*XW1*2;
  short* predcata   = (short*)(ws + o); o += (size_t)BB*PW*2;
  short* predcatb   = (short*)(ws + o); o += (size_t)BB*PW*2;
  short* hb         = (short*)(ws + o); o += (size_t)BH*2;
  float* cbuf       = (float*)(ws + o); o += (size_t)2*BH*4;
  float* bias0i     = (float*)(ws + o); o += (size_t)G4H*4;
  float* bias1i     = (float*)(ws + o); o += (size_t)G4H*4;
  float* P0         = (float*)(ws + o); o += (size_t)BB*G4H*4;
  (void)ws_size; (void)in_sizes; (void)n_in; (void)out_size;

  cvt_encout<<<16384, 256, 0, stream>>>(enc_out_bf, enc_out);
  build_wcat_bf<<<22528, 256, 0, stream>>>(wcat0i, wcat1i,
      (const float*)d_in[9], (const float*)d_in[10], (const float*)d_in[13], (const float*)d_in[14]);
  prep_misc<<<8720, 256, 0, stream>>>(cbuf, xcat0a, xcat1a, hb, wdecT, wenc_bf, wout_bf, emb_bf,
      bias0i, bias1i, c0, h0, W_dec, W_enc, (const float*)d_in[17], emb,
      b_ih0, b_hh0, b_ih1, b_hh1);
  enc_gemm<<<dim3(HH/128, (BB*SS)/64), 256, 0, stream>>>(
      enc_proj_bf, enc_out_bf, wenc_bf, DENC, HH);

  short* xc0[2] = {xcat0a, xcat0b};
  short* xc1[2] = {xcat1a, xcat1b};
  short* pc[2]  = {predcata, predcatb};
  for (int t = 0; t < TT; ++t) {
    // A: attn + partial-gates0(emb,h0prev)->P0 + out(t-1)
    attn_pg0<<<528, 256, 0, stream>>>(enc_proj_bf, enc_out_bf, v, mask, targets, emb_bf,
        hb, wdecT, xc0[t&1], pc[t&1], wcat0i, P0, pc[(t+1)&1], wout_bf, b_out, out, t);
    // B: gates0 finish (ctx K) + LSTM0 + emb prewrite for t+1
    gates0_fin<<<264, 256, 0, stream>>>(
        xc0[t&1], wcat0i, bias0i, P0, cbuf, xc1[t&1], xc0[(t+1)&1] + EE + DENC,
        xc0[(t+1)&1], targets, emb_bf, t);
    // C: gates1 full + LSTM1
    gates1_full<<<256, 256, 0, stream>>>(
        xc1[t&1], wcat1i, bias1i, cbuf + BH, xc1[(t+1)&1] + HH, pc[t&1], hb);
  }
  out_fin<<<16, 256, 0, stream>>>(pc[1], wout_bf, b_out, out);
}

// Round 7
// 2674.051 us; speedup vs baseline: 8.5902x; 1.0458x over previous
//
#include <hip/hip_runtime.h>
#include <math.h>

#define BB 512
#define SS 64
#define TT 32
#define VV 128
#define EE 256
#define HH 512
#define DENC 1024
#define BH (BB*HH)
#define XW0 1792   // E + DENC + H
#define XW1 1024   // H + H
#define PW  1792   // H + DENC + E
#define G4H 2048   // 4*H

typedef __attribute__((ext_vector_type(8))) short bf16x8;
typedef __attribute__((ext_vector_type(4))) short bf16x4;
typedef __attribute__((ext_vector_type(4))) float f32x4;

__device__ __forceinline__ float sigf(float x){ return 1.f/(1.f+expf(-x)); }
__device__ __forceinline__ float bf2f(short s){
  return __uint_as_float(((unsigned)(unsigned short)s) << 16);
}
__device__ __forceinline__ short f2bf(float f){
  unsigned u = __float_as_uint(f);
  return (short)((u + 0x7FFF + ((u>>16)&1)) >> 16);   // RNE
}
__device__ __forceinline__ float tanh_fast(float x){
  x = fminf(fmaxf(x, -15.f), 15.f);
  float e = __expf(2.f*x);
  return (e - 1.f) / (e + 1.f);
}

__device__ __forceinline__ void zacc(f32x4 a[2][2]){
  #pragma unroll
  for (int i = 0; i < 2; ++i)
    #pragma unroll
    for (int j = 0; j < 2; ++j) a[i][j] = {0.f,0.f,0.f,0.f};
}

// Double-buffered pipelined bf16 MFMA GEMM core. BK=64, one barrier per iter.
// LDS row stride 72 shorts (2-way bank aliasing only).
// Wave w computes tile (BM/2)x(BN/2) at wm=(w>>1)*(BM/2), wn=(w&1)*(BN/2).
template<int BM, int BN>
struct GemmPipe {
  static constexpr int LA = 72;
  static __device__ __forceinline__ void run(short* Asb, short* Bsb,
      const short* __restrict__ A, const short* __restrict__ Bt,
      int lda, int ldb, int kBase, int nIter,
      int rowBase, int colBase, int tid, f32x4 acc[BM/32][BN/32])
  {
    constexpr int FI = BM/32, FJ = BN/32, ACH = BM/32, BCH = BN/32;
    const int lane = tid & 63, wave = tid >> 6;
    const int ml = lane & 15, kq = lane >> 4;
    const int wm = (wave >> 1)*(BM/2), wn = (wave & 1)*(BN/2);
    const int arow = (tid*ACH) >> 3, acol = ((tid*ACH) & 7)*8;
    const int brow = (tid*BCH) >> 3, bcol = ((tid*BCH) & 7)*8;
    const short* Ap = A + (size_t)(rowBase+arow)*lda + kBase + acol;
    const short* Bp = Bt + (size_t)(colBase+brow)*ldb + kBase + bcol;
    bf16x8 ar[ACH], br[BCH];
    #pragma unroll
    for (int c = 0; c < ACH; ++c) ar[c] = *(const bf16x8*)(Ap + c*8);
    #pragma unroll
    for (int c = 0; c < BCH; ++c) br[c] = *(const bf16x8*)(Bp + c*8);
    for (int i = 0; i < nIter; ++i) {
      short* Ab = Asb + (i&1)*(BM*LA);
      short* Bb = Bsb + (i&1)*(BN*LA);
      #pragma unroll
      for (int c = 0; c < ACH; ++c) *(bf16x8*)&Ab[arow*LA + acol + c*8] = ar[c];
      #pragma unroll
      for (int c = 0; c < BCH; ++c) *(bf16x8*)&Bb[brow*LA + bcol + c*8] = br[c];
      __syncthreads();
      if (i+1 < nIter) {
        const short* An = Ap + (size_t)(i+1)*64;
        const short* Bn = Bp + (size_t)(i+1)*64;
        #pragma unroll
        for (int c = 0; c < ACH; ++c) ar[c] = *(const bf16x8*)(An + c*8);
        #pragma unroll
        for (int c = 0; c < BCH; ++c) br[c] = *(const bf16x8*)(Bn + c*8);
      }
      #pragma unroll
      for (int kh = 0; kh < 2; ++kh) {
        bf16x8 af[FI], bfv[FJ];
        #pragma unroll
        for (int ii = 0; ii < FI; ++ii)
          af[ii] = *(const bf16x8*)&Ab[(wm + ii*16 + ml)*LA + kh*32 + kq*8];
        #pragma unroll
        for (int jj = 0; jj < FJ; ++jj)
          bfv[jj] = *(const bf16x8*)&Bb[(wn + jj*16 + ml)*LA + kh*32 + kq*8];
        #pragma unroll
        for (int ii = 0; ii < FI; ++ii)
          #pragma unroll
          for (int jj = 0; jj < FJ; ++jj)
            acc[ii][jj] = __builtin_amdgcn_mfma_f32_16x16x32_bf16(af[ii], bfv[jj], acc[ii][jj], 0,0,0);
      }
    }
    __syncthreads();
  }
};

// ---------------- shared device roles ----------------

// attention for b = 2*aid, 2*aid+1 (256 threads). Writes ctx into xcat0/predcat
// and emb into predcat. Does NOT write xcat0 emb (prewritten one step ahead).
__device__ __forceinline__ void attn_role(int aid, int tid, char* smem, int t,
    const short* __restrict__ enc_proj, const short* __restrict__ enc_out,
    const float* __restrict__ vvec, const int* __restrict__ mask,
    const int* __restrict__ targets, const short* __restrict__ embb,
    const short* __restrict__ hb, const short* __restrict__ wdecT,
    short* __restrict__ xcat0, short* __restrict__ predcat)
{
  const int b0 = aid*2;
  float* hbf = (float*)smem;                  // [2][512]
  float* dps = (float*)(smem + 4096);         // [ksel][b][512]
  float* vvf = (float*)(smem + 12288);        // [512]
  float* sc  = (float*)(smem + 14336);        // [2][64]
  float* wt  = (float*)(smem + 14848);        // [2][64]
  {
    bf16x4 h4 = *(const bf16x4*)&hb[(size_t)b0*HH + tid*4];
    #pragma unroll
    for (int j = 0; j < 4; ++j) hbf[tid*4 + j] = bf2f(h4[j]);
    vvf[tid] = vvec[tid];
    vvf[256 + tid] = vvec[256 + tid];
  }
  __syncthreads();
  // dec_proj partials: unit=(b,h8), 2 threads per unit (k-halves of 256)
  {
    int unit = tid & 127, ksel = tid >> 7;
    int bb = unit >> 6, h8 = unit & 63;
    const short* wp = wdecT + (size_t)(ksel*256)*HH + h8*8;
    const float* hrow = hbf + bb*HH + ksel*256;
    float a[8] = {0.f,0.f,0.f,0.f,0.f,0.f,0.f,0.f};
    for (int k = 0; k < 256; ++k) {
      bf16x8 w8 = *(const bf16x8*)(wp + (size_t)k*HH);
      float x = hrow[k];
      #pragma unroll
      for (int j = 0; j < 8; ++j) a[j] += x * bf2f(w8[j]);
    }
    float* d = dps + (ksel*2 + bb)*HH + h8*8;
    #pragma unroll
    for (int j = 0; j < 8; ++j) d[j] = a[j];
  }
  __syncthreads();
  {   // combine k-halves
    int bb = tid >> 7, h0_ = (tid & 127)*4;
    f32x4 s0 = *(f32x4*)&dps[bb*HH + h0_];
    f32x4 s1 = *(f32x4*)&dps[(2 + bb)*HH + h0_];
    *(f32x4*)&dps[bb*HH + h0_] = s0 + s1;
  }
  __syncthreads();
  // scores: unit=(b,s), 2 lanes per unit (h-halves of 256)
  {
    int u = tid >> 1, khalf = tid & 1;
    int bb = u >> 6, s = u & 63;
    const short* ep = enc_proj + ((size_t)(b0+bb)*SS + s)*HH + khalf*256;
    const float* dpp = dps + bb*HH + khalf*256;
    const float* vp  = vvf + khalf*256;
    float accv = 0.f;
    for (int hc = 0; hc < 32; ++hc) {
      bf16x8 e8 = *(const bf16x8*)(ep + hc*8);
      f32x4 d0 = *(const f32x4*)(dpp + hc*8);
      f32x4 d1 = *(const f32x4*)(dpp + hc*8 + 4);
      f32x4 v0 = *(const f32x4*)(vp + hc*8);
      f32x4 v1 = *(const f32x4*)(vp + hc*8 + 4);
      #pragma unroll
      for (int j = 0; j < 4; ++j) accv += v0[j]*tanh_fast(d0[j] + bf2f(e8[j]));
      #pragma unroll
      for (int j = 0; j < 4; ++j) accv += v1[j]*tanh_fast(d1[j] + bf2f(e8[4+j]));
    }
    accv += __shfl_xor(accv, 1, 64);
    if (khalf == 0) sc[bb*64 + s] = accv;
  }
  __syncthreads();
  if (tid < 128) {   // masked softmax: wave0 -> b0, wave1 -> b1
    int bb = tid >> 6, s = tid & 63;
    int valid = mask[(b0+bb)*SS + s];
    float x = valid ? sc[bb*64 + s] : -INFINITY;
    float mx = x;
    #pragma unroll
    for (int off = 32; off; off >>= 1) mx = fmaxf(mx, __shfl_xor(mx, off, 64));
    float e = valid ? __expf(x - mx) : 0.f;
    float sum = e;
    #pragma unroll
    for (int off = 32; off; off >>= 1) sum += __shfl_xor(sum, off, 64);
    wt[bb*64 + s] = e / sum;
  }
  __syncthreads();
  {   // context
    int bb = tid >> 7, d0 = (tid & 127)*8;
    const short* eob = enc_out + (size_t)(b0+bb)*SS*DENC + d0;
    float ca[8] = {0.f,0.f,0.f,0.f,0.f,0.f,0.f,0.f};
    for (int s = 0; s < SS; ++s) {
      float w = wt[bb*64 + s];
      bf16x8 e8 = *(const bf16x8*)(eob + (size_t)s*DENC);
      #pragma unroll
      for (int j = 0; j < 8; ++j) ca[j] += w * bf2f(e8[j]);
    }
    bf16x8 cb8;
    #pragma unroll
    for (int j = 0; j < 8; ++j) cb8[j] = f2bf(ca[j]);
    int b_ = b0 + bb;
    *(bf16x8*)&xcat0[(size_t)b_*XW0 + EE + d0] = cb8;
    *(bf16x8*)&predcat[(size_t)b_*PW + HH + d0] = cb8;
  }
  #pragma unroll
  for (int bb = 0; bb < 2; ++bb) {   // predcat emb (xcat0 emb prewritten)
    int b_ = b0 + bb;
    int tok = (t == 0) ? 2 : targets[b_*TT + t - 1];
    predcat[(size_t)b_*PW + HH + DENC + tid] = embb[tok*EE + tid];
  }
}

// out GEMM for one 64x64 tile (full K): out[:, t-1, :] = predprev @ wout.T + b_out
__device__ __forceinline__ void out_role(int idx, int tid, char* smem,
    const short* __restrict__ predprev, const short* __restrict__ wout,
    const float* __restrict__ b_out, float* __restrict__ out, int t)
{
  short* As = (short*)smem;
  short* Bs = (short*)(smem + 18432);
  const int rowBase = (idx >> 1)*64, colBase = (idx & 1)*64;
  f32x4 acc[2][2];
  zacc(acc);
  GemmPipe<64,64>::run(As, Bs, predprev, wout, PW, PW, 0, PW/64, rowBase, colBase, tid, acc);
  const int lane = tid & 63, wave = tid >> 6, ml = lane & 15, kq = lane >> 4;
  const int wm = (wave >> 1)*32, wn = (wave & 1)*32;
  #pragma unroll
  for (int ii = 0; ii < 2; ++ii)
    #pragma unroll
    for (int jj = 0; jj < 2; ++jj) {
      int n = colBase + wn + jj*16 + ml;
      float bv = b_out[n];
      #pragma unroll
      for (int r2 = 0; r2 < 4; ++r2) {
        int m = rowBase + wm + ii*16 + kq*4 + r2;
        out[(size_t)m*(TT*VV) + (size_t)(t-1)*VV + n] = acc[ii][jj][r2] + bv;
      }
    }
}

// store f32 partial accumulator tile to P[512][G4H]
__device__ __forceinline__ void pstore(int tid, int rowBase, int colBase,
    float* __restrict__ P, f32x4 acc[2][2])
{
  const int lane = tid & 63, wave = tid >> 6, ml = lane & 15, kq = lane >> 4;
  const int wm = (wave >> 1)*32, wn = (wave & 1)*32;
  #pragma unroll
  for (int ii = 0; ii < 2; ++ii)
    #pragma unroll
    for (int jj = 0; jj < 2; ++jj)
      #pragma unroll
      for (int r2 = 0; r2 < 4; ++r2)
        P[(size_t)(rowBase + wm + ii*16 + kq*4 + r2)*G4H + colBase + wn + jj*16 + ml] = acc[ii][jj][r2];
}

// LSTM cell epilogue (gate cols n = 4*h + gate, interleaved)
__device__ __forceinline__ void gates_epi(int tid, int rowBase, int colBase,
    char* smem, f32x4 acc[2][2], const float* __restrict__ bias,
    float* __restrict__ cb,
    short* __restrict__ d1, int ld1, short* __restrict__ d2, int ld2,
    short* __restrict__ d3)
{
  const int lane = tid & 63, wave = tid >> 6, ml = lane & 15, kq = lane >> 4;
  const int wm = (wave >> 1)*32, wn = (wave & 1)*32;
  float* Ct = (float*)smem;                    // 64*68*4 = 17408 <= 18432
  float bj0 = bias[colBase + wn + ml];
  float bj1 = bias[colBase + wn + 16 + ml];
  #pragma unroll
  for (int ii = 0; ii < 2; ++ii)
    #pragma unroll
    for (int jj = 0; jj < 2; ++jj)
      #pragma unroll
      for (int r2 = 0; r2 < 4; ++r2)
        Ct[(wm + ii*16 + kq*4 + r2)*68 + wn + jj*16 + ml] = acc[ii][jj][r2] + (jj ? bj1 : bj0);
  __syncthreads();
  #pragma unroll
  for (int kk = 0; kk < 4; ++kk) {
    int cidx = tid + kk*256;
    int m = cidx >> 4, hl = cidx & 15;
    float4 gv = *(float4*)&Ct[m*68 + hl*4];    // i,f,g,o
    int b_ = rowBase + m, h_ = (colBase >> 2) + hl;
    float cp = cb[b_*HH + h_];
    float cn = sigf(gv.y)*cp + sigf(gv.x)*tanhf(gv.z);
    float hn = sigf(gv.w)*tanhf(cn);
    cb[b_*HH + h_] = cn;
    short hb16 = f2bf(hn);
    d1[(size_t)b_*ld1 + h_] = hb16;
    d2[(size_t)b_*ld2 + h_] = hb16;
    if (d3) d3[(size_t)b_*HH + h_] = hb16;
  }
}

// write emb(token for step t+1) into next xcat0 buffer: 64 b-rows from rowBase
__device__ __forceinline__ void emb_prewrite(int rowBase, int tid,
    short* __restrict__ xc0n, const int* __restrict__ targets,
    const short* __restrict__ embb, int t)
{
  int b_ = rowBase + (tid >> 2);
  int tok = targets[b_*TT + t];
  const short* src = embb + tok*EE + (tid & 3)*64;
  short* dst = xc0n + (size_t)b_*XW0 + (tid & 3)*64;
  #pragma unroll
  for (int j = 0; j < 8; ++j)
    *(bf16x8*)(dst + j*8) = *(const bf16x8*)(src + j*8);
}

// ---------------- per-step kernels ----------------

// Launch A (800 blocks):
//  [0,256)   attn (2 rows each)
//  [256,512) partial-gates0 K = emb[0,256) U h0prev[1280,1792) -> P0
//  [512,768) partial-gates1 K = h1prev[512,1024) -> P1
//  [768,800) out-GEMM(t-1) K-halves (14 iters each) -> Pout f32 partials
// No intra-launch dependencies: pg0 reads xcat0 cols disjoint from attn's ctx
// writes; pg1 reads xcat1 cols written at step t-1; out reads predcat(t-1).
__global__ __launch_bounds__(256)
void attn_pg01(const short* __restrict__ enc_proj, const short* __restrict__ enc_out,
               const float* __restrict__ vvec, const int* __restrict__ mask,
               const int* __restrict__ targets, const short* __restrict__ embb,
               const short* __restrict__ hb, const short* __restrict__ wdecT,
               short* __restrict__ xcat0, short* __restrict__ predcat,
               const short* __restrict__ wcat0, float* __restrict__ P0,
               const short* __restrict__ xcat1, const short* __restrict__ wcat1,
               float* __restrict__ P1,
               const short* __restrict__ predprev, const short* __restrict__ wout,
               float* __restrict__ Pout, int t)
{
  __shared__ __align__(16) char smem[36864];
  const int tid = threadIdx.x, bid = blockIdx.x;
  if (bid < 256) {
    attn_role(bid, tid, smem, t, enc_proj, enc_out, vvec, mask, targets,
              embb, hb, wdecT, xcat0, predcat);
  } else if (bid < 512) {
    short* As = (short*)smem;
    short* Bs = (short*)(smem + 18432);
    int idx = bid - 256;
    int rowBase = (idx >> 5)*64, colBase = (idx & 31)*64;
    f32x4 acc[2][2];
    zacc(acc);
    GemmPipe<64,64>::run(As, Bs, xcat0, wcat0, XW0, XW0, 0,    4, rowBase, colBase, tid, acc);
    GemmPipe<64,64>::run(As, Bs, xcat0, wcat0, XW0, XW0, 1280, 8, rowBase, colBase, tid, acc);
    pstore(tid, rowBase, colBase, P0, acc);
  } else if (bid < 768) {
    short* As = (short*)smem;
    short* Bs = (short*)(smem + 18432);
    int idx = bid - 512;
    int rowBase = (idx >> 5)*64, colBase = (idx & 31)*64;
    f32x4 acc[2][2];
    zacc(acc);
    GemmPipe<64,64>::run(As, Bs, xcat1, wcat1, XW1, XW1, 512, 8, rowBase, colBase, tid, acc);
    pstore(tid, rowBase, colBase, P1, acc);
  } else {
    if (t >= 1) {
      short* As = (short*)smem;
      short* Bs = (short*)(smem + 18432);
      int idx = bid - 768;            // 0..31
      int half = idx >> 4, oIdx = idx & 15;
      int rowBase = (oIdx >> 1)*64, colBase = (oIdx & 1)*64;
      f32x4 acc[2][2];
      zacc(acc);
      GemmPipe<64,64>::run(As, Bs, predprev, wout, PW, PW, half*896, 14,
                           rowBase, colBase, tid, acc);
      const int lane = tid & 63, wave = tid >> 6, ml = lane & 15, kq = lane >> 4;
      const int wm = (wave >> 1)*32, wn = (wave & 1)*32;
      float* Pt = Pout + half*65536;
      #pragma unroll
      for (int ii = 0; ii < 2; ++ii)
        #pragma unroll
        for (int jj = 0; jj < 2; ++jj)
          #pragma unroll
          for (int r2 = 0; r2 < 4; ++r2)
            Pt[(rowBase + wm + ii*16 + kq*4 + r2)*VV + colBase + wn + jj*16 + ml] = acc[ii][jj][r2];
    }
  }
}

// Launch B (272 blocks): [0,256) gates0 finish (ctx K, 16 iters, seeded from P0)
// + LSTM0; [256,264) emb prewrite for t+1; [264,272) out(t-1) combine.
__global__ __launch_bounds__(256)
void gates0_fin(const short* __restrict__ A, const short* __restrict__ W,
                const float* __restrict__ bias, const float* __restrict__ P0,
                float* __restrict__ cb,
                short* __restrict__ d1, short* __restrict__ d2,
                short* __restrict__ xc0n, const int* __restrict__ targets,
                const short* __restrict__ embb,
                const float* __restrict__ Pout, const float* __restrict__ b_out,
                float* __restrict__ out, int t)
{
  __shared__ __align__(16) char smem[36864];
  const int tid = threadIdx.x, bid = blockIdx.x;
  if (bid >= 264) {
    if (t >= 1) {                     // combine out halves for step t-1
      int base = (bid - 264)*8192 + tid*32;
      #pragma unroll
      for (int j = 0; j < 8; ++j) {
        int i = base + j*4;
        f32x4 a = *(const f32x4*)&Pout[i];
        f32x4 b = *(const f32x4*)&Pout[65536 + i];
        int m = i >> 7, n = i & 127;
        f32x4 bo = *(const f32x4*)&b_out[n];
        f32x4 r = a + b + bo;
        *(f32x4*)&out[(size_t)m*(TT*VV) + (size_t)(t-1)*VV + n] = r;
      }
    }
    return;
  }
  if (bid >= 256) {
    if (t + 1 < TT) emb_prewrite((bid - 256)*64, tid, xc0n, targets, embb, t);
    return;
  }
  short* As = (short*)smem;
  short* Bs = (short*)(smem + 18432);
  const int rowBase = (bid >> 5)*64, colBase = (bid & 31)*64;
  const int lane = tid & 63, wave = tid >> 6, ml = lane & 15, kq = lane >> 4;
  const int wm = (wave >> 1)*32, wn = (wave & 1)*32;
  f32x4 acc[2][2];
  const float* Pp = P0 + (size_t)rowBase*G4H + colBase;
  #pragma unroll
  for (int ii = 0; ii < 2; ++ii)
    #pragma unroll
    for (int jj = 0; jj < 2; ++jj)
      #pragma unroll
      for (int r2 = 0; r2 < 4; ++r2)
        acc[ii][jj][r2] = Pp[(wm + ii*16 + kq*4 + r2)*G4H + wn + jj*16 + ml];
  GemmPipe<64,64>::run(As, Bs, A, W, XW0, XW0, 256, 16, rowBase, colBase, tid, acc);
  gates_epi(tid, rowBase, colBase, smem, acc, bias, cb, d1, XW1, d2, XW0, (short*)nullptr);
}

// Launch C: gates1 finish (h0n K = [0,512), 8 iters, seeded from P1) + LSTM1.
__global__ __launch_bounds__(256)
void gates1_fin(const short* __restrict__ A, const short* __restrict__ W,
                const float* __restrict__ bias, const float* __restrict__ P1,
                float* __restrict__ cb,
                short* __restrict__ d1, short* __restrict__ d2, short* __restrict__ d3)
{
  __shared__ __align__(16) char smem[36864];
  const int tid = threadIdx.x, bid = blockIdx.x;
  short* As = (short*)smem;
  short* Bs = (short*)(smem + 18432);
  const int rowBase = (bid >> 5)*64, colBase = (bid & 31)*64;
  const int lane = tid & 63, wave = tid >> 6, ml = lane & 15, kq = lane >> 4;
  const int wm = (wave >> 1)*32, wn = (wave & 1)*32;
  f32x4 acc[2][2];
  const float* Pp = P1 + (size_t)rowBase*G4H + colBase;
  #pragma unroll
  for (int ii = 0; ii < 2; ++ii)
    #pragma unroll
    for (int jj = 0; jj < 2; ++jj)
      #pragma unroll
      for (int r2 = 0; r2 < 4; ++r2)
        acc[ii][jj][r2] = Pp[(wm + ii*16 + kq*4 + r2)*G4H + wn + jj*16 + ml];
  GemmPipe<64,64>::run(As, Bs, A, W, XW1, XW1, 0, 8, rowBase, colBase, tid, acc);
  gates_epi(tid, rowBase, colBase, smem, acc, bias, cb, d1, XW1, d2, PW, d3);
}

// trailing out-GEMM for the final step (full K, once)
__global__ __launch_bounds__(256)
void out_fin(const short* __restrict__ predprev, const short* __restrict__ wout,
             const float* __restrict__ b_out, float* __restrict__ out)
{
  __shared__ __align__(16) char smem[36864];
  out_role(blockIdx.x, threadIdx.x, smem, predprev, wout, b_out, out, TT);
}

// enc_proj = enc_out @ W_enc.T (M=32768, N=512, K=1024), bf16 out. BM=64, BN=128.
__global__ __launch_bounds__(256)
void enc_gemm(short* __restrict__ C, const short* __restrict__ A, const short* __restrict__ Bt,
              int K, int ldc)
{
  __shared__ __align__(16) char smem[55296];
  short* As = (short*)smem;                    // 2*64*72*2  = 18432
  short* Bs = (short*)(smem + 18432);          // 2*128*72*2 = 36864
  const int tid = threadIdx.x;
  const int rowBase = blockIdx.y*64, colBase = blockIdx.x*128;
  f32x4 acc[2][4];
  #pragma unroll
  for (int i = 0; i < 2; ++i)
    #pragma unroll
    for (int j = 0; j < 4; ++j) acc[i][j] = {0.f,0.f,0.f,0.f};
  GemmPipe<64,128>::run(As, Bs, A, Bt, K, K, 0, K >> 6, rowBase, colBase, tid, acc);
  const int lane = tid & 63, wave = tid >> 6, ml = lane & 15, kq = lane >> 4;
  const int wm = (wave >> 1)*32, wn = (wave & 1)*64;
  #pragma unroll
  for (int ii = 0; ii < 2; ++ii)
    #pragma unroll
    for (int jj = 0; jj < 4; ++jj) {
      int n = colBase + wn + jj*16 + ml;
      #pragma unroll
      for (int r2 = 0; r2 < 4; ++r2) {
        int m = rowBase + wm + ii*16 + kq*4 + r2;
        C[(size_t)m*ldc + n] = f2bf(acc[ii][jj][r2]);
      }
    }
}

// interleaved (n = 4*h + gate) bf16 weight concat
__global__ __launch_bounds__(256)
void build_wcat_bf(short* __restrict__ wcat0, short* __restrict__ wcat1,
                   const float* __restrict__ wih0, const float* __restrict__ whh0,
                   const float* __restrict__ wih1, const float* __restrict__ whh1)
{
  int idx = blockIdx.x*256 + threadIdx.x;
  const int N0 = G4H*XW0;
  if (idx < N0) {
    int n = idx / XW0, k = idx % XW0;
    int row = (n & 3)*HH + (n >> 2);
    float v = (k < EE+DENC) ? wih0[(size_t)row*(EE+DENC) + k] : whh0[(size_t)row*HH + (k - (EE+DENC))];
    wcat0[idx] = f2bf(v);
  } else {
    int j = idx - N0;
    int n = j / XW1, k = j % XW1;
    int row = (n & 3)*HH + (n >> 2);
    float v = (k < HH) ? wih1[(size_t)row*HH + k] : whh1[(size_t)row*HH + (k - HH)];
    wcat1[j] = f2bf(v);
  }
}

__global__ __launch_bounds__(256)
void cvt_encout(short* __restrict__ dst, const float* __restrict__ src)
{
  size_t i8 = ((size_t)blockIdx.x*256 + threadIdx.x)*8;
  float4 a = *(const float4*)&src[i8];
  float4 b = *(const float4*)&src[i8+4];
  bf16x8 o;
  o[0]=f2bf(a.x); o[1]=f2bf(a.y); o[2]=f2bf(a.z); o[3]=f2bf(a.w);
  o[4]=f2bf(b.x); o[5]=f2bf(b.y); o[6]=f2bf(b.z); o[7]=f2bf(b.w);
  *(bf16x8*)&dst[i8] = o;
}

__global__ __launch_bounds__(256)
void prep_misc(float* __restrict__ cbuf, short* __restrict__ xcat0a, short* __restrict__ xcat1a,
               short* __restrict__ hb, short* __restrict__ wdecT, short* __restrict__ wenc,
               short* __restrict__ wout, short* __restrict__ embb,
               float* __restrict__ bias0i, float* __restrict__ bias1i,
               const float* __restrict__ c0, const float* __restrict__ h0,
               const float* __restrict__ W_dec, const float* __restrict__ W_enc,
               const float* __restrict__ W_out, const float* __restrict__ emb,
               const float* __restrict__ b_ih0, const float* __restrict__ b_hh0,
               const float* __restrict__ b_ih1, const float* __restrict__ b_hh1)
{
  int idx = blockIdx.x*256 + threadIdx.x;
  if (idx < 524288) { cbuf[idx] = c0[idx]; return; }
  idx -= 524288;
  if (idx < 262144) {
    int b = idx >> 9, h = idx & 511;
    xcat0a[(size_t)b*XW0 + EE + DENC + h] = f2bf(h0[idx]);
    return;
  }
  idx -= 262144;
  if (idx < 262144) {
    int b = idx >> 9, h = idx & 511;
    short v = f2bf(h0[BH + idx]);
    xcat1a[(size_t)b*XW1 + HH + h] = v;
    hb[idx] = v;
    return;
  }
  idx -= 262144;
  if (idx < 262144) {                           // wdecT[k][n] = W_dec[n][k]
    int k = idx >> 9, n = idx & 511;
    wdecT[idx] = f2bf(W_dec[(size_t)n*HH + k]);
    return;
  }
  idx -= 262144;
  if (idx < 524288) { wenc[idx] = f2bf(W_enc[idx]); return; }
  idx -= 524288;
  if (idx < 229376) { wout[idx] = f2bf(W_out[idx]); return; }
  idx -= 229376;
  if (idx < 32768)  { embb[idx] = f2bf(emb[idx]); return; }
  idx -= 32768;
  if (idx < 2048) {
    int row = (idx & 3)*HH + (idx >> 2);
    bias0i[idx] = b_ih0[row] + b_hh0[row];
    return;
  }
  idx -= 2048;
  if (idx < 2048) {
    int row = (idx & 3)*HH + (idx >> 2);
    bias1i[idx] = b_ih1[row] + b_hh1[row];
    return;
  }
  idx -= 2048;
  {                                             // emb(t=0) = emb[EOS=2] into xcat0a
    int b = idx >> 8, e = idx & 255;
    xcat0a[(size_t)b*XW0 + e] = f2bf(emb[2*EE + e]);
  }
}

extern "C" void kernel_launch(void* const* d_in, const int* in_sizes, int n_in,
                              void* d_out, int out_size, void* d_ws, size_t ws_size,
                              hipStream_t stream) {
  const float* enc_out = (const float*)d_in[0];
  const float* h0      = (const float*)d_in[1];
  const float* c0      = (const float*)d_in[2];
  const int*   targets = (const int*)d_in[3];
  const int*   mask    = (const int*)d_in[4];
  const float* emb     = (const float*)d_in[5];
  const float* W_enc   = (const float*)d_in[6];
  const float* W_dec   = (const float*)d_in[7];
  const float* v       = (const float*)d_in[8];
  const float* b_ih0   = (const float*)d_in[11];
  const float* b_hh0   = (const float*)d_in[12];
  const float* b_ih1   = (const float*)d_in[15];
  const float* b_hh1   = (const float*)d_in[16];
  const float* b_out   = (const float*)d_in[18];
  float* out = (float*)d_out;

  char* ws = (char*)d_ws;
  size_t o = 0;
  short* enc_out_bf = (short*)(ws + o); o += (size_t)BB*SS*DENC*2;
  short* enc_proj_bf= (short*)(ws + o); o += (size_t)BB*SS*HH*2;
  short* wcat0i     = (short*)(ws + o); o += (size_t)G4H*XW0*2;
  short* wcat1i     = (short*)(ws + o); o += (size_t)G4H*XW1*2;
  short* wdecT      = (short*)(ws + o); o += (size_t)HH*HH*2;
  short* wenc_bf    = (short*)(ws + o); o += (size_t)HH*DENC*2;
  short* wout_bf    = (short*)(ws + o); o += (size_t)VV*PW*2;
  short* emb_bf     = (short*)(ws + o); o += (size_t)VV*EE*2;
  short* xcat0a     = (short*)(ws + o); o += (size_t)BB*XW0*2;
  short* xcat0b     = (short*)(ws + o); o += (size_t)BB*XW0*2;
  short* xcat1a     = (short*)(ws + o); o += (size_t)BB*XW1*2;
  short* xcat1b     = (short*)(ws + o); o += (size_t)BB*XW1*2;
  short* predcata   = (short*)(ws + o); o += (size_t)BB*PW*2;
  short* predcatb   = (short*)(ws + o); o += (size_t)BB*PW*2;
  short* hb         = (short*)(ws + o); o += (size_t)BH*2;
  float* cbuf       = (float*)(ws + o); o += (size_t)2*BH*4;
  float* bias0i     = (float*)(ws + o); o += (size_t)G4H*4;
  float* bias1i     = (float*)(ws + o); o += (size_t)G4H*4;
  float* P0         = (float*)(ws + o); o += (size_t)BB*G4H*4;
  float* P1         = (float*)(ws + o); o += (size_t)BB*G4H*4;
  float* Pout       = (float*)(ws + o); o += (size_t)2*BB*VV*4;
  (void)ws_size; (void)in_sizes; (void)n_in; (void)out_size;

  cvt_encout<<<16384, 256, 0, stream>>>(enc_out_bf, enc_out);
  build_wcat_bf<<<22528, 256, 0, stream>>>(wcat0i, wcat1i,
      (const float*)d_in[9], (const float*)d_in[10], (const float*)d_in[13], (const float*)d_in[14]);
  prep_misc<<<8720, 256, 0, stream>>>(cbuf, xcat0a, xcat1a, hb, wdecT, wenc_bf, wout_bf, emb_bf,
      bias0i, bias1i, c0, h0, W_dec, W_enc, (const float*)d_in[17], emb,
      b_ih0, b_hh0, b_ih1, b_hh1);
  enc_gemm<<<dim3(HH/128, (BB*SS)/64), 256, 0, stream>>>(
      enc_proj_bf, enc_out_bf, wenc_bf, DENC, HH);

  short* xc0[2] = {xcat0a, xcat0b};
  short* xc1[2] = {xcat1a, xcat1b};
  short* pc[2]  = {predcata, predcatb};
  for (int t = 0; t < TT; ++t) {
    // A: attn + pg0(emb,h0prev)->P0 + pg1(h1prev)->P1 + out(t-1) K-halves->Pout
    attn_pg01<<<800, 256, 0, stream>>>(enc_proj_bf, enc_out_bf, v, mask, targets, emb_bf,
        hb, wdecT, xc0[t&1], pc[t&1], wcat0i, P0, xc1[t&1], wcat1i, P1,
        pc[(t+1)&1], wout_bf, Pout, t);
    // B: gates0 finish (ctx K) + LSTM0 + emb prewrite(t+1) + out(t-1) combine
    gates0_fin<<<272, 256, 0, stream>>>(
        xc0[t&1], wcat0i, bias0i, P0, cbuf, xc1[t&1], xc0[(t+1)&1] + EE + DENC,
        xc0[(t+1)&1], targets, emb_bf, Pout, b_out, out, t);
    // C: gates1 finish (h0n K) + LSTM1
    gates1_fin<<<256, 256, 0, stream>>>(
        xc1[t&1], wcat1i, bias1i, P1, cbuf + BH, xc1[(t+1)&1] + HH, pc[t&1], hb);
  }
  out_fin<<<16, 256, 0, stream>>>(pc[1], wout_bf, b_out, out);
}